// Round 8
// baseline (1001.938 us; speedup 1.0000x reference)
//
#include <hip/hip_runtime.h>
#include <hip/hip_cooperative_groups.h>
#include <math.h>

namespace cg = cooperative_groups;

#define HW 2304       // 48*48
#define NC 256        // channels
#define NPIX 2500     // 50*50 padded grid (channel-last buffer)
#define NPIXP 2560    // padded row stride for channel-first buffers / Gram
#define MATSZ 65536   // 256*256
#define NS_ITERS 5    // e5 ~ 7e-9 from e0=0.644; f32-converged
#define NSGRID 512    // 2 blocks/CU, co-resident for cooperative launch
#define NSLAB 6
#define KSLAB 384     // 2304/6

typedef unsigned long long u64;

// ---------------- means (f64) ----------------
__global__ void mean_kernel(const float* __restrict__ c, const float* __restrict__ s,
                            double* __restrict__ mean) {
  int ch = blockIdx.x, m = blockIdx.y;
  const float* src = (m < 2 ? c + m * (NC * HW) : s + (m - 2) * (NC * HW)) + ch * HW;
  double acc = 0.0;
  for (int n = threadIdx.x; n < HW; n += 64) acc += (double)src[n];
  for (int o = 32; o > 0; o >>= 1) acc += __shfl_down(acc, o);
  if (threadIdx.x == 0) mean[m * NC + ch] = acc / (double)HW;
}

// ---------------- covariance partials: raw sum(x*y), 64x64 tile, 4x4/thread ----------------
__launch_bounds__(256)
__global__ void cov_part(const float* __restrict__ c, const float* __restrict__ s,
                         float* __restrict__ covp) {
  int z = blockIdx.z;
  int m = z / NSLAB, slab = z % NSLAB;
  const float* src = (m < 2 ? c + m * (NC * HW) : s + (m - 2) * (NC * HW));
  int i0 = blockIdx.y * 64, j0 = blockIdx.x * 64;
  int kb = slab * KSLAB;
  __shared__ float As[16][64], Bs[16][64];
  int tx = threadIdx.x, ty = threadIdx.y;
  int tid = ty * 16 + tx;
  int li = tid >> 2;        // row 0..63
  int lk4 = tid & 3;        // float4 group along k
  float acc[4][4] = {};
  for (int kc = 0; kc < KSLAB; kc += 16) {
    __syncthreads();
    float4 va = *(const float4*)&src[(u64)(i0 + li) * HW + kb + kc + lk4 * 4];
    float4 vb = *(const float4*)&src[(u64)(j0 + li) * HW + kb + kc + lk4 * 4];
    As[lk4 * 4 + 0][li] = va.x; As[lk4 * 4 + 1][li] = va.y;
    As[lk4 * 4 + 2][li] = va.z; As[lk4 * 4 + 3][li] = va.w;
    Bs[lk4 * 4 + 0][li] = vb.x; Bs[lk4 * 4 + 1][li] = vb.y;
    Bs[lk4 * 4 + 2][li] = vb.z; Bs[lk4 * 4 + 3][li] = vb.w;
    __syncthreads();
    #pragma unroll
    for (int kk = 0; kk < 16; ++kk) {
      float4 a = *(const float4*)&As[kk][ty * 4];
      float4 b = *(const float4*)&Bs[kk][tx * 4];
      float av[4] = {a.x, a.y, a.z, a.w};
      float bv[4] = {b.x, b.y, b.z, b.w};
      #pragma unroll
      for (int i = 0; i < 4; ++i)
        #pragma unroll
        for (int j = 0; j < 4; ++j) acc[i][j] += av[i] * bv[j];
    }
  }
  float* Cp = covp + (u64)z * MATSZ;
  #pragma unroll
  for (int i = 0; i < 4; ++i) {
    float4 v = make_float4(acc[i][0], acc[i][1], acc[i][2], acc[i][3]);
    *(float4*)&Cp[(i0 + ty * 4 + i) * NC + j0 + tx * 4] = v;
  }
}

// grid(256,4), block 256: cov = sum(slabs) - HW*mu_i*mu_j; diag -> snorm (trace fused)
__global__ void cov_reduce(const float* __restrict__ covp, const double* __restrict__ mean,
                           float* __restrict__ cov, double* __restrict__ snorm) {
  int m = blockIdx.y;
  int row = blockIdx.x, col = threadIdx.x;
  int e = row * 256 + col;
  float v = 0.0f;
  #pragma unroll
  for (int slab = 0; slab < NSLAB; ++slab)
    v += covp[(u64)(m * NSLAB + slab) * MATSZ + e];
  double mi = mean[m * NC + row], mj = mean[m * NC + col];
  float res = (float)((double)v - (double)HW * mi * mj);
  cov[m * MATSZ + e] = res;
  if (col == row) atomicAdd(&snorm[m], 1.25 * (double)res / 256.0);
}

// ---------------- cooperative Newton-Schulz: init + 5 coupled iterations ----------------
// 32x32 tile GEMM over K=256, 2x2/thread, k-major LDS (float2 reads).
__device__ __forceinline__ void gemm32_tile(const float* __restrict__ A, const float* __restrict__ B,
                                            float* __restrict__ C, int m0, int n0,
                                            float (*As)[36], float (*Bs)[36], bool isT) {
  int tid = threadIdx.x;
  int tx = tid & 15, ty = tid >> 4;
  int ar = tid >> 3, ac4 = (tid & 7) * 4;   // A stage: row ar, k-group ac4 (transpose on write)
  int bk = tid >> 3, bc4 = (tid & 7) * 4;   // B stage: k-row bk, col-group bc4
  float acc00 = 0.f, acc01 = 0.f, acc10 = 0.f, acc11 = 0.f;
  for (int k0 = 0; k0 < 256; k0 += 32) {
    __syncthreads();
    float4 va = *(const float4*)&A[(m0 + ar) * NC + k0 + ac4];
    As[ac4 + 0][ar] = va.x; As[ac4 + 1][ar] = va.y;
    As[ac4 + 2][ar] = va.z; As[ac4 + 3][ar] = va.w;
    *(float4*)&Bs[bk][bc4] = *(const float4*)&B[(k0 + bk) * NC + n0 + bc4];
    __syncthreads();
    #pragma unroll
    for (int kk = 0; kk < 32; ++kk) {
      float2 a = *(const float2*)&As[kk][ty * 2];
      float2 b = *(const float2*)&Bs[kk][tx * 2];
      acc00 += a.x * b.x; acc01 += a.x * b.y;
      acc10 += a.y * b.x; acc11 += a.y * b.y;
    }
  }
  int r0 = m0 + ty * 2, c0 = n0 + tx * 2;
  if (isT) {
    float2 v0 = make_float2((r0 == c0 ? 1.5f : 0.f) - 0.5f * acc00,
                            (r0 == c0 + 1 ? 1.5f : 0.f) - 0.5f * acc01);
    float2 v1 = make_float2((r0 + 1 == c0 ? 1.5f : 0.f) - 0.5f * acc10,
                            (r0 + 1 == c0 + 1 ? 1.5f : 0.f) - 0.5f * acc11);
    *(float2*)&C[r0 * NC + c0] = v0;
    *(float2*)&C[(r0 + 1) * NC + c0] = v1;
  } else {
    *(float2*)&C[r0 * NC + c0] = make_float2(acc00, acc01);
    *(float2*)&C[(r0 + 1) * NC + c0] = make_float2(acc10, acc11);
  }
}

__launch_bounds__(256, 2)
__global__ void ns_coop(const float* __restrict__ cov, const double* __restrict__ snorm,
                        float* __restrict__ Ya, float* __restrict__ Za,
                        float* __restrict__ Yb, float* __restrict__ Zb,
                        float* __restrict__ T) {
  cg::grid_group grid = cg::this_grid();
  __shared__ float As[32][36], Bs[32][36];
  int blk = blockIdx.x;
  int tid = threadIdx.x;
  // init: Y = cov/s, Z = I
  for (int e = blk * 256 + tid; e < 4 * MATSZ; e += NSGRID * 256) {
    int m = e >> 16, idx = e & 65535;
    float inv = (float)(1.0 / snorm[m]);
    Ya[e] = cov[e] * inv;
    Za[e] = ((idx >> 8) == (idx & 255)) ? 1.0f : 0.0f;
  }
  grid.sync();
  const float *Yc = Ya, *Zc = Za;
  float *Yn = Yb, *Zn = Zb;
  for (int it = 0; it < NS_ITERS; ++it) {
    if (blk < 256) {                         // T = 1.5I - 0.5 * Z * Y
      int m = blk >> 6, tile = blk & 63;
      int m0 = (tile >> 3) * 32, n0 = (tile & 7) * 32;
      gemm32_tile(Zc + m * MATSZ, Yc + m * MATSZ, T + m * MATSZ, m0, n0, As, Bs, true);
    }
    grid.sync();
    {
      int j = blk & 255;
      int m = j >> 6, tile = j & 63;
      int m0 = (tile >> 3) * 32, n0 = (tile & 7) * 32;
      if (blk < 256)                         // Yn = Y * T
        gemm32_tile(Yc + m * MATSZ, T + m * MATSZ, Yn + m * MATSZ, m0, n0, As, Bs, false);
      else                                   // Zn = T * Z
        gemm32_tile(T + m * MATSZ, Zc + m * MATSZ, Zn + m * MATSZ, m0, n0, As, Bs, false);
    }
    grid.sync();
    const float* t1 = Yc; Yc = Yn; Yn = (float*)t1;
    const float* t2 = Zc; Zc = Zn; Zn = (float*)t2;
  }
  // NS_ITERS=5 (odd): final Y in Yb, Z in Zb
}

// ---------------- whitening apply -> padded norm buffers ----------------
__launch_bounds__(256)
__global__ void whiten_kernel(const float* __restrict__ c, const float* __restrict__ s,
                              const float* __restrict__ Zf,
                              const double* __restrict__ snorm, const double* __restrict__ mean,
                              float* __restrict__ padC_cf, float* __restrict__ padS_cf,
                              float* __restrict__ padS_cl) {
  int mat = blockIdx.z;
  const float* src = (mat < 2 ? c + mat * (NC * HW) : s + (mat - 2) * (NC * HW));
  const float* A = Zf + mat * MATSZ;
  const double* mn = mean + mat * NC;
  float wscale = (float)(1.0 / sqrt(snorm[mat]));
  int m0 = blockIdx.y * 32, n0 = blockIdx.x * 64;
  __shared__ float As[32][33];
  __shared__ float Bs[32][65];
  int tx = threadIdx.x, ty = threadIdx.y;
  int tid = ty * 16 + tx;
  float acc[2][4] = {};
  for (int k0 = 0; k0 < 256; k0 += 32) {
    __syncthreads();
    #pragma unroll
    for (int l = 0; l < 4; ++l) {
      int idx = tid + l * 256;
      int r = idx >> 5, cc = idx & 31;
      As[r][cc] = A[(m0 + r) * NC + k0 + cc];
    }
    #pragma unroll
    for (int l = 0; l < 8; ++l) {
      int idx = tid + l * 256;
      int kk = idx >> 6, nn = idx & 63;
      Bs[kk][nn] = src[(k0 + kk) * HW + n0 + nn] - (float)mn[k0 + kk];
    }
    __syncthreads();
    #pragma unroll
    for (int kk = 0; kk < 32; ++kk) {
      float a0 = As[ty][kk], a1 = As[ty + 16][kk];
      float b0 = Bs[kk][tx], b1 = Bs[kk][tx + 16], b2 = Bs[kk][tx + 32], b3 = Bs[kk][tx + 48];
      acc[0][0] += a0 * b0; acc[0][1] += a0 * b1; acc[0][2] += a0 * b2; acc[0][3] += a0 * b3;
      acc[1][0] += a1 * b0; acc[1][1] += a1 * b1; acc[1][2] += a1 * b2; acc[1][3] += a1 * b3;
    }
  }
  #pragma unroll
  for (int i = 0; i < 2; ++i) {
    int row = m0 + ty + 16 * i;
    #pragma unroll
    for (int j = 0; j < 4; ++j) {
      int n = n0 + tx + 16 * j;
      float v = acc[i][j] * wscale;
      int y = n / 48, x = n % 48;
      int ppos = (y + 1) * 50 + (x + 1);
      if (mat < 2) {
        padC_cf[(u64)mat * (NC * NPIXP) + row * NPIXP + ppos] = v;
      } else {
        padS_cf[(u64)(mat - 2) * (NC * NPIXP) + row * NPIXP + ppos] = v;
        padS_cl[(u64)(mat - 2) * (NPIX * NC) + ppos * NC + row] = v;
      }
    }
  }
}

// ---------------- patch norms: rknorm = 1/||ker(ps)|| ----------------
__global__ void knorm_kernel(const float* __restrict__ padS_cl, float* __restrict__ rknorm) {
  int ps = blockIdx.x, b = blockIdx.y;
  int ys = ps / 48, xs = ps % 48;
  const float* S = padS_cl + (u64)b * (NPIX * NC);
  int ch = threadIdx.x;
  double acc = 0.0;
  #pragma unroll
  for (int dy = 0; dy < 3; ++dy)
    #pragma unroll
    for (int dx = 0; dx < 3; ++dx) {
      float v = S[((ys + dy) * 50 + xs + dx) * NC + ch];
      acc += (double)v * (double)v;
    }
  __shared__ double sd[256];
  int t = threadIdx.x;
  sd[t] = acc; __syncthreads();
  for (int st = 128; st > 0; st >>= 1) {
    if (t < st) sd[t] += sd[t + st];
    __syncthreads();
  }
  if (ch == 0) rknorm[b * HW + ps] = (float)(1.0 / sqrt(sd[0]));
}

// ---------------- pixel Gram: G[p][q] = sum_ch padC[ch][p]*padS[ch][q] ----------------
// 128x64 tile, 8x4 per thread, conflict-free LDS, reg-prefetch pipeline. grid(20,40).
__launch_bounds__(256)
__global__ void gram_gemm(const float* __restrict__ padC_cf, const float* __restrict__ padS_cf,
                          float* __restrict__ G, int b) {
  const float* A = padC_cf + (u64)b * (NC * NPIXP);
  const float* B = padS_cf + (u64)b * (NC * NPIXP);
  int p0 = blockIdx.x * 128, q0 = blockIdx.y * 64;
  __shared__ float As[16][128], Bs[16][64];
  int tx = threadIdx.x, ty = threadIdx.y;
  int tid = ty * 16 + tx;
  int ar0 = tid >> 5, ac0 = (tid & 31) << 2;
  int ar1 = ar0 + 8;
  int br = tid >> 4, bc = (tid & 15) << 2;
  // prefetch chunk 0
  float4 pa0 = *(const float4*)&A[(u64)ar0 * NPIXP + p0 + ac0];
  float4 pa1 = *(const float4*)&A[(u64)ar1 * NPIXP + p0 + ac0];
  float4 pb  = *(const float4*)&B[(u64)br * NPIXP + q0 + bc];
  float acc[8][4] = {};
  for (int k0 = 0; k0 < 256; k0 += 16) {
    __syncthreads();
    *(float4*)&As[ar0][ac0] = pa0;
    *(float4*)&As[ar1][ac0] = pa1;
    *(float4*)&Bs[br][bc]   = pb;
    __syncthreads();
    if (k0 + 16 < 256) {   // issue next chunk's loads; latency hides under compute
      pa0 = *(const float4*)&A[(u64)(k0 + 16 + ar0) * NPIXP + p0 + ac0];
      pa1 = *(const float4*)&A[(u64)(k0 + 16 + ar1) * NPIXP + p0 + ac0];
      pb  = *(const float4*)&B[(u64)(k0 + 16 + br) * NPIXP + q0 + bc];
    }
    #pragma unroll
    for (int kk = 0; kk < 16; ++kk) {
      float4 a0 = *(const float4*)&As[kk][ty * 8];      // 4 distinct addrs/wave: conflict-free
      float4 a1 = *(const float4*)&As[kk][ty * 8 + 4];
      float4 bv4 = *(const float4*)&Bs[kk][tx * 4];     // 16 addrs over 256B: 2-way (free)
      float av[8] = {a0.x, a0.y, a0.z, a0.w, a1.x, a1.y, a1.z, a1.w};
      float bv[4] = {bv4.x, bv4.y, bv4.z, bv4.w};
      #pragma unroll
      for (int i = 0; i < 8; ++i)
        #pragma unroll
        for (int j = 0; j < 4; ++j) acc[i][j] += av[i] * bv[j];
    }
  }
  #pragma unroll
  for (int i = 0; i < 8; ++i) {
    float4 v = make_float4(acc[i][0], acc[i][1], acc[i][2], acc[i][3]);
    *(float4*)&G[(u64)(p0 + ty * 8 + i) * NPIXP + q0 + tx * 4] = v;
  }
}

// ---------------- fused stencil + argmax ----------------
__launch_bounds__(256)
__global__ void scoremax_kernel(const float* __restrict__ G, const float* __restrict__ rknorm,
                                u64* __restrict__ rmax, int b) {
  int y = blockIdx.x, ys = blockIdx.y;
  __shared__ float Gt[3][50][50];
  __shared__ float sc[48][48];
  __shared__ float rkl[48];
  int tid = threadIdx.x;
  for (int t = tid; t < 7500; t += 256) {
    int dy = t / 2500, rem = t % 2500;
    int u = rem / 50, v = rem - u * 50;
    Gt[dy][u][v] = G[(u64)((y + dy) * 50 + u) * NPIXP + (ys + dy) * 50 + v];
  }
  if (tid < 48) rkl[tid] = rknorm[b * HW + ys * 48 + tid];
  __syncthreads();
  #pragma unroll
  for (int k = 0; k < 9; ++k) {
    int idx = tid + k * 256;
    int x = idx / 48, xs = idx - x * 48;
    float v = 0.0f;
    #pragma unroll
    for (int dy = 0; dy < 3; ++dy)
      #pragma unroll
      for (int dx = 0; dx < 3; ++dx)
        v += Gt[dy][x + dx][xs + dx];
    sc[x][xs] = v * rkl[xs];
  }
  __syncthreads();
  if (tid < 48) {
    float best = -1e30f; int bxs = 0;
    for (int xs = 0; xs < 48; ++xs) {
      float v = sc[tid][xs];
      if (v > best) { best = v; bxs = xs; }   // strict >: smallest xs on ties
    }
    int ps = ys * 48 + bxs;
    unsigned ub = __float_as_uint(best);
    unsigned enc = (ub & 0x80000000u) ? ~ub : (ub | 0x80000000u);
    u64 key = ((u64)enc << 32) | (u64)(2303 - ps);
    atomicMax(&rmax[(u64)b * HW + y * 48 + tid], key);
  }
}

// ---------------- reassemble: paste chosen patches + overlap normalize ----------------
__global__ void reassemble_kernel(const float* __restrict__ padS_cl, const u64* __restrict__ rmax,
                                  float* __restrict__ rF_cl) {
  int pix = blockIdx.x, b = blockIdx.y;
  int y = pix / 48, x = pix % 48;
  const u64* rm = rmax + (u64)b * HW;
  const float* S = padS_cl + (u64)b * (NPIX * NC);
  int ch = threadIdx.x;
  float sum = 0.0f;
  #pragma unroll
  for (int i = 0; i < 3; ++i)
    #pragma unroll
    for (int j = 0; j < 3; ++j) {
      int yn = y + 1 - i, xn = x + 1 - j;
      if (yn >= 0 && yn < 48 && xn >= 0 && xn < 48) {
        int ps = 2303 - (int)(unsigned)(rm[yn * 48 + xn] & 0xFFFFFFFFu);
        int ys = ps / 48, xs = ps % 48;
        sum += S[((ys + i) * 50 + xs + j) * NC + ch];
      }
    }
  float cy = (y == 0 || y == 47) ? 2.0f : 3.0f;
  float cx = (x == 0 || x == 47) ? 2.0f : 3.0f;
  rF_cl[(u64)b * (HW * NC) + pix * NC + ch] = sum / (cy * cx);
}

// ---------------- coloring: out = sqrt(s)*Yf*rF + mean_s ----------------
__launch_bounds__(256)
__global__ void coloring_kernel(const float* __restrict__ Yf, const double* __restrict__ snorm,
                                const double* __restrict__ mean, const float* __restrict__ rF_cl,
                                float* __restrict__ out) {
  int b = blockIdx.z;
  const float* A = Yf + (2 + b) * MATSZ;
  const float* Bp = rF_cl + (u64)b * (HW * NC);
  const double* mn = mean + (2 + b) * NC;
  float cscale = (float)sqrt(snorm[2 + b]);
  int m0 = blockIdx.y * 32, n0 = blockIdx.x * 64;
  __shared__ float As[32][33];
  __shared__ float Bs[32][65];
  int tx = threadIdx.x, ty = threadIdx.y;
  int tid = ty * 16 + tx;
  float acc[2][4] = {};
  for (int k0 = 0; k0 < 256; k0 += 32) {
    __syncthreads();
    #pragma unroll
    for (int l = 0; l < 4; ++l) {
      int idx = tid + l * 256;
      int r = idx >> 5, cc = idx & 31;
      As[r][cc] = A[(m0 + r) * NC + k0 + cc];
    }
    #pragma unroll
    for (int l = 0; l < 8; ++l) {
      int idx = tid + l * 256;
      int kk = idx & 31, nn = idx >> 5;
      Bs[kk][nn] = Bp[(u64)(n0 + nn) * NC + k0 + kk];
    }
    __syncthreads();
    #pragma unroll
    for (int kk = 0; kk < 32; ++kk) {
      float a0 = As[ty][kk], a1 = As[ty + 16][kk];
      float b0 = Bs[kk][tx], b1 = Bs[kk][tx + 16], b2 = Bs[kk][tx + 32], b3 = Bs[kk][tx + 48];
      acc[0][0] += a0 * b0; acc[0][1] += a0 * b1; acc[0][2] += a0 * b2; acc[0][3] += a0 * b3;
      acc[1][0] += a1 * b0; acc[1][1] += a1 * b1; acc[1][2] += a1 * b2; acc[1][3] += a1 * b3;
    }
  }
  #pragma unroll
  for (int i = 0; i < 2; ++i) {
    int row = m0 + ty + 16 * i;
    float madd = (float)mn[row];
    #pragma unroll
    for (int j = 0; j < 4; ++j) {
      int n = n0 + tx + 16 * j;
      out[(u64)b * (NC * HW) + row * HW + n] = acc[i][j] * cscale + madd;
    }
  }
}

// ---------------- host ----------------
extern "C" void kernel_launch(void* const* d_in, const int* in_sizes, int n_in,
                              void* d_out, int out_size, void* d_ws, size_t ws_size,
                              hipStream_t stream) {
  const float* c = (const float*)d_in[0];
  const float* s = (const float*)d_in[1];
  float* out = (float*)d_out;

  char* ws = (char*)d_ws;
  size_t off = 0;
  auto alloc = [&](size_t bytes) {
    void* p = ws + off;
    off = (off + bytes + 255) & ~(size_t)255;
    return p;
  };
  double* mean   = (double*)alloc(4 * NC * sizeof(double));
  float* cov     = (float*)alloc((size_t)4 * MATSZ * sizeof(float));
  float* covp    = (float*)alloc((size_t)4 * NSLAB * MATSZ * sizeof(float));
  float* Ya      = (float*)alloc((size_t)4 * MATSZ * sizeof(float));
  float* Yb      = (float*)alloc((size_t)4 * MATSZ * sizeof(float));
  float* Za      = (float*)alloc((size_t)4 * MATSZ * sizeof(float));
  float* Zb      = (float*)alloc((size_t)4 * MATSZ * sizeof(float));
  float* T       = (float*)alloc((size_t)4 * MATSZ * sizeof(float));
  float* padC_cf = (float*)alloc((size_t)2 * NC * NPIXP * sizeof(float));
  float* padS_cf = (float*)alloc((size_t)2 * NC * NPIXP * sizeof(float));
  float* padS_cl = (float*)alloc((size_t)2 * NPIX * NC * sizeof(float));
  float* rknorm  = (float*)alloc((size_t)2 * HW * sizeof(float));
  float* rF_cl   = (float*)alloc((size_t)2 * HW * NC * sizeof(float));
  float* G       = (float*)alloc((size_t)NPIXP * NPIXP * sizeof(float)); // per-batch Gram
  u64*   rmax    = (u64*)alloc((size_t)2 * HW * sizeof(u64));
  double* snorm  = (double*)alloc(4 * sizeof(double));

  size_t padBytes = (size_t)(2 * NC * NPIXP + 2 * NC * NPIXP + 2 * NPIX * NC) * sizeof(float);
  hipMemsetAsync(padC_cf, 0, padBytes, stream);
  hipMemsetAsync(rmax, 0, (size_t)2 * HW * sizeof(u64) + 4 * sizeof(double), stream);

  mean_kernel<<<dim3(256, 4), 64, 0, stream>>>(c, s, mean);
  cov_part<<<dim3(4, 4, 4 * NSLAB), dim3(16, 16), 0, stream>>>(c, s, covp);
  cov_reduce<<<dim3(256, 4), 256, 0, stream>>>(covp, mean, cov, snorm);

  {
    void* args[] = {(void*)&cov, (void*)&snorm, (void*)&Ya, (void*)&Za,
                    (void*)&Yb, (void*)&Zb, (void*)&T};
    hipLaunchCooperativeKernel((void*)ns_coop, dim3(NSGRID), dim3(256), args, 0, stream);
  }
  // NS_ITERS=5 (odd): final Y in Yb, Z in Zb

  whiten_kernel<<<dim3(36, 8, 4), dim3(16, 16), 0, stream>>>(c, s, Zb, snorm, mean,
                                                             padC_cf, padS_cf, padS_cl);
  knorm_kernel<<<dim3(2304, 2), 256, 0, stream>>>(padS_cl, rknorm);

  for (int b = 0; b < 2; ++b) {
    gram_gemm<<<dim3(20, 40), dim3(16, 16), 0, stream>>>(padC_cf, padS_cf, G, b);
    scoremax_kernel<<<dim3(48, 48), 256, 0, stream>>>(G, rknorm, rmax, b);
  }

  reassemble_kernel<<<dim3(2304, 2), 256, 0, stream>>>(padS_cl, rmax, rF_cl);
  coloring_kernel<<<dim3(36, 8, 2), dim3(16, 16), 0, stream>>>(Yb, snorm, mean, rF_cl, out);
}

// Round 9
// 435.975 us; speedup vs baseline: 2.2982x; 2.2982x over previous
//
#include <hip/hip_runtime.h>
#include <math.h>

#define HW 2304       // 48*48
#define NC 256        // channels
#define NPIX 2500     // 50*50 padded grid (channel-last buffer)
#define NPIXP 2560    // padded row stride for channel-first buffers / Gram
#define MATSZ 65536   // 256*256
#define NS_ITERS 5    // e5 ~ 7e-9 from e0=0.644; f32-converged
#define NSLAB 6
#define KSLAB 384     // 2304/6

typedef unsigned long long u64;

// ---------------- means (f64) ----------------
__global__ void mean_kernel(const float* __restrict__ c, const float* __restrict__ s,
                            double* __restrict__ mean) {
  int ch = blockIdx.x, m = blockIdx.y;
  const float* src = (m < 2 ? c + m * (NC * HW) : s + (m - 2) * (NC * HW)) + ch * HW;
  double acc = 0.0;
  for (int n = threadIdx.x; n < HW; n += 64) acc += (double)src[n];
  for (int o = 32; o > 0; o >>= 1) acc += __shfl_down(acc, o);
  if (threadIdx.x == 0) mean[m * NC + ch] = acc / (double)HW;
}

// ---------------- covariance partials: raw sum(x*y), 64x64 tile, 4x4/thread ----------------
__launch_bounds__(256)
__global__ void cov_part(const float* __restrict__ c, const float* __restrict__ s,
                         float* __restrict__ covp) {
  int z = blockIdx.z;
  int m = z / NSLAB, slab = z % NSLAB;
  const float* src = (m < 2 ? c + m * (NC * HW) : s + (m - 2) * (NC * HW));
  int i0 = blockIdx.y * 64, j0 = blockIdx.x * 64;
  int kb = slab * KSLAB;
  __shared__ float As[16][64], Bs[16][64];
  int tx = threadIdx.x, ty = threadIdx.y;
  int tid = ty * 16 + tx;
  int li = tid >> 2;        // row 0..63
  int lk4 = tid & 3;        // float4 group along k
  float acc[4][4] = {};
  for (int kc = 0; kc < KSLAB; kc += 16) {
    __syncthreads();
    float4 va = *(const float4*)&src[(u64)(i0 + li) * HW + kb + kc + lk4 * 4];
    float4 vb = *(const float4*)&src[(u64)(j0 + li) * HW + kb + kc + lk4 * 4];
    As[lk4 * 4 + 0][li] = va.x; As[lk4 * 4 + 1][li] = va.y;
    As[lk4 * 4 + 2][li] = va.z; As[lk4 * 4 + 3][li] = va.w;
    Bs[lk4 * 4 + 0][li] = vb.x; Bs[lk4 * 4 + 1][li] = vb.y;
    Bs[lk4 * 4 + 2][li] = vb.z; Bs[lk4 * 4 + 3][li] = vb.w;
    __syncthreads();
    #pragma unroll
    for (int kk = 0; kk < 16; ++kk) {
      float4 a = *(const float4*)&As[kk][ty * 4];
      float4 b = *(const float4*)&Bs[kk][tx * 4];
      float av[4] = {a.x, a.y, a.z, a.w};
      float bv[4] = {b.x, b.y, b.z, b.w};
      #pragma unroll
      for (int i = 0; i < 4; ++i)
        #pragma unroll
        for (int j = 0; j < 4; ++j) acc[i][j] += av[i] * bv[j];
    }
  }
  float* Cp = covp + (u64)z * MATSZ;
  #pragma unroll
  for (int i = 0; i < 4; ++i) {
    float4 v = make_float4(acc[i][0], acc[i][1], acc[i][2], acc[i][3]);
    *(float4*)&Cp[(i0 + ty * 4 + i) * NC + j0 + tx * 4] = v;
  }
}

// grid(256,4), block 256: cov = sum(slabs) - HW*mu_i*mu_j; diag -> snorm (trace fused)
__global__ void cov_reduce(const float* __restrict__ covp, const double* __restrict__ mean,
                           float* __restrict__ cov, double* __restrict__ snorm) {
  int m = blockIdx.y;
  int row = blockIdx.x, col = threadIdx.x;
  int e = row * 256 + col;
  float v = 0.0f;
  #pragma unroll
  for (int slab = 0; slab < NSLAB; ++slab)
    v += covp[(u64)(m * NSLAB + slab) * MATSZ + e];
  double mi = mean[m * NC + row], mj = mean[m * NC + col];
  float res = (float)((double)v - (double)HW * mi * mj);
  cov[m * MATSZ + e] = res;
  if (col == row) atomicAdd(&snorm[m], 1.25 * (double)res / 256.0);
}

__global__ void ns_init(const float* __restrict__ cov, const double* __restrict__ snorm,
                        float* __restrict__ Y, float* __restrict__ Z) {
  int m = blockIdx.y;
  int e = blockIdx.x * 256 + threadIdx.x;
  double inv = 1.0 / snorm[m];
  Y[m * MATSZ + e] = (float)((double)cov[m * MATSZ + e] * inv);
  Z[m * MATSZ + e] = ((e >> 8) == (e & 255)) ? 1.0f : 0.0f;
}

// ---------------- Newton-Schulz GEMMs (256x256x256, f32) ----------------
__launch_bounds__(256)
__global__ void ns_gemm_T(const float* __restrict__ Zc, const float* __restrict__ Yc,
                          float* __restrict__ T) {
  int m = blockIdx.z;
  const float* A = Zc + m * MATSZ;
  const float* B = Yc + m * MATSZ;
  int m0 = blockIdx.y * 32, n0 = blockIdx.x * 32;
  __shared__ float As[32][33], Bs[32][33];
  int tx = threadIdx.x, ty = threadIdx.y;
  int tid = ty * 16 + tx;
  float acc[2][2] = {};
  for (int k0 = 0; k0 < 256; k0 += 32) {
    __syncthreads();
    #pragma unroll
    for (int l = 0; l < 4; ++l) {
      int idx = tid + l * 256;
      int r = idx >> 5, cc = idx & 31;
      As[r][cc] = A[(m0 + r) * NC + k0 + cc];
      Bs[r][cc] = B[(k0 + r) * NC + n0 + cc];
    }
    __syncthreads();
    #pragma unroll
    for (int kk = 0; kk < 32; ++kk) {
      float a0 = As[ty][kk], a1 = As[ty + 16][kk];
      float b0 = Bs[kk][tx], b1 = Bs[kk][tx + 16];
      acc[0][0] += a0 * b0; acc[0][1] += a0 * b1;
      acc[1][0] += a1 * b0; acc[1][1] += a1 * b1;
    }
  }
  float* Cp = T + m * MATSZ;
  #pragma unroll
  for (int i = 0; i < 2; ++i)
    #pragma unroll
    for (int j = 0; j < 2; ++j) {
      int row = m0 + ty + 16 * i, col = n0 + tx + 16 * j;
      Cp[row * NC + col] = (row == col ? 1.5f : 0.0f) - 0.5f * acc[i][j];
    }
}

__launch_bounds__(256)
__global__ void ns_gemm_YZ(const float* __restrict__ Yc, const float* __restrict__ Zc,
                           const float* __restrict__ T,
                           float* __restrict__ Yn, float* __restrict__ Zn) {
  int z = blockIdx.z;
  int m = z & 3;
  bool isY = (z < 4);
  const float* A = isY ? (Yc + m * MATSZ) : (T + m * MATSZ);
  const float* B = isY ? (T + m * MATSZ) : (Zc + m * MATSZ);
  float* Cp = isY ? (Yn + m * MATSZ) : (Zn + m * MATSZ);
  int m0 = blockIdx.y * 32, n0 = blockIdx.x * 32;
  __shared__ float As[32][33], Bs[32][33];
  int tx = threadIdx.x, ty = threadIdx.y;
  int tid = ty * 16 + tx;
  float acc[2][2] = {};
  for (int k0 = 0; k0 < 256; k0 += 32) {
    __syncthreads();
    #pragma unroll
    for (int l = 0; l < 4; ++l) {
      int idx = tid + l * 256;
      int r = idx >> 5, cc = idx & 31;
      As[r][cc] = A[(m0 + r) * NC + k0 + cc];
      Bs[r][cc] = B[(k0 + r) * NC + n0 + cc];
    }
    __syncthreads();
    #pragma unroll
    for (int kk = 0; kk < 32; ++kk) {
      float a0 = As[ty][kk], a1 = As[ty + 16][kk];
      float b0 = Bs[kk][tx], b1 = Bs[kk][tx + 16];
      acc[0][0] += a0 * b0; acc[0][1] += a0 * b1;
      acc[1][0] += a1 * b0; acc[1][1] += a1 * b1;
    }
  }
  #pragma unroll
  for (int i = 0; i < 2; ++i)
    #pragma unroll
    for (int j = 0; j < 2; ++j)
      Cp[(m0 + ty + 16 * i) * NC + n0 + tx + 16 * j] = acc[i][j];
}

// ---------------- whitening apply -> padded norm buffers ----------------
__launch_bounds__(256)
__global__ void whiten_kernel(const float* __restrict__ c, const float* __restrict__ s,
                              const float* __restrict__ Zf,
                              const double* __restrict__ snorm, const double* __restrict__ mean,
                              float* __restrict__ padC_cf, float* __restrict__ padS_cf,
                              float* __restrict__ padS_cl) {
  int mat = blockIdx.z;
  const float* src = (mat < 2 ? c + mat * (NC * HW) : s + (mat - 2) * (NC * HW));
  const float* A = Zf + mat * MATSZ;
  const double* mn = mean + mat * NC;
  float wscale = (float)(1.0 / sqrt(snorm[mat]));
  int m0 = blockIdx.y * 32, n0 = blockIdx.x * 64;
  __shared__ float As[32][33];
  __shared__ float Bs[32][65];
  int tx = threadIdx.x, ty = threadIdx.y;
  int tid = ty * 16 + tx;
  float acc[2][4] = {};
  for (int k0 = 0; k0 < 256; k0 += 32) {
    __syncthreads();
    #pragma unroll
    for (int l = 0; l < 4; ++l) {
      int idx = tid + l * 256;
      int r = idx >> 5, cc = idx & 31;
      As[r][cc] = A[(m0 + r) * NC + k0 + cc];
    }
    #pragma unroll
    for (int l = 0; l < 8; ++l) {
      int idx = tid + l * 256;
      int kk = idx >> 6, nn = idx & 63;
      Bs[kk][nn] = src[(k0 + kk) * HW + n0 + nn] - (float)mn[k0 + kk];
    }
    __syncthreads();
    #pragma unroll
    for (int kk = 0; kk < 32; ++kk) {
      float a0 = As[ty][kk], a1 = As[ty + 16][kk];
      float b0 = Bs[kk][tx], b1 = Bs[kk][tx + 16], b2 = Bs[kk][tx + 32], b3 = Bs[kk][tx + 48];
      acc[0][0] += a0 * b0; acc[0][1] += a0 * b1; acc[0][2] += a0 * b2; acc[0][3] += a0 * b3;
      acc[1][0] += a1 * b0; acc[1][1] += a1 * b1; acc[1][2] += a1 * b2; acc[1][3] += a1 * b3;
    }
  }
  #pragma unroll
  for (int i = 0; i < 2; ++i) {
    int row = m0 + ty + 16 * i;
    #pragma unroll
    for (int j = 0; j < 4; ++j) {
      int n = n0 + tx + 16 * j;
      float v = acc[i][j] * wscale;
      int y = n / 48, x = n % 48;
      int ppos = (y + 1) * 50 + (x + 1);
      if (mat < 2) {
        padC_cf[(u64)mat * (NC * NPIXP) + row * NPIXP + ppos] = v;
      } else {
        padS_cf[(u64)(mat - 2) * (NC * NPIXP) + row * NPIXP + ppos] = v;
        padS_cl[(u64)(mat - 2) * (NPIX * NC) + ppos * NC + row] = v;
      }
    }
  }
}

// ---------------- patch norms: rknorm = 1/||ker(ps)|| ----------------
__global__ void knorm_kernel(const float* __restrict__ padS_cl, float* __restrict__ rknorm) {
  int ps = blockIdx.x, b = blockIdx.y;
  int ys = ps / 48, xs = ps % 48;
  const float* S = padS_cl + (u64)b * (NPIX * NC);
  int ch = threadIdx.x;
  double acc = 0.0;
  #pragma unroll
  for (int dy = 0; dy < 3; ++dy)
    #pragma unroll
    for (int dx = 0; dx < 3; ++dx) {
      float v = S[((ys + dy) * 50 + xs + dx) * NC + ch];
      acc += (double)v * (double)v;
    }
  __shared__ double sd[256];
  int t = threadIdx.x;
  sd[t] = acc; __syncthreads();
  for (int st = 128; st > 0; st >>= 1) {
    if (t < st) sd[t] += sd[t + st];
    __syncthreads();
  }
  if (ch == 0) rknorm[b * HW + ps] = (float)(1.0 / sqrt(sd[0]));
}

// ---------------- pixel Gram: G[p][q] = sum_ch padC[ch][p]*padS[ch][q] ----------------
// 128x64 tile, 8x4 per thread, conflict-free LDS, reg-prefetch pipeline. grid(20,40).
__launch_bounds__(256)
__global__ void gram_gemm(const float* __restrict__ padC_cf, const float* __restrict__ padS_cf,
                          float* __restrict__ G, int b) {
  const float* A = padC_cf + (u64)b * (NC * NPIXP);
  const float* B = padS_cf + (u64)b * (NC * NPIXP);
  int p0 = blockIdx.x * 128, q0 = blockIdx.y * 64;
  __shared__ float As[16][128], Bs[16][64];
  int tx = threadIdx.x, ty = threadIdx.y;
  int tid = ty * 16 + tx;
  int ar0 = tid >> 5, ac0 = (tid & 31) << 2;
  int ar1 = ar0 + 8;
  int br = tid >> 4, bc = (tid & 15) << 2;
  // prefetch chunk 0
  float4 pa0 = *(const float4*)&A[(u64)ar0 * NPIXP + p0 + ac0];
  float4 pa1 = *(const float4*)&A[(u64)ar1 * NPIXP + p0 + ac0];
  float4 pb  = *(const float4*)&B[(u64)br * NPIXP + q0 + bc];
  float acc[8][4] = {};
  for (int k0 = 0; k0 < 256; k0 += 16) {
    __syncthreads();
    *(float4*)&As[ar0][ac0] = pa0;
    *(float4*)&As[ar1][ac0] = pa1;
    *(float4*)&Bs[br][bc]   = pb;
    __syncthreads();
    if (k0 + 16 < 256) {   // issue next chunk's loads; latency hides under compute
      pa0 = *(const float4*)&A[(u64)(k0 + 16 + ar0) * NPIXP + p0 + ac0];
      pa1 = *(const float4*)&A[(u64)(k0 + 16 + ar1) * NPIXP + p0 + ac0];
      pb  = *(const float4*)&B[(u64)(k0 + 16 + br) * NPIXP + q0 + bc];
    }
    #pragma unroll
    for (int kk = 0; kk < 16; ++kk) {
      float4 a0 = *(const float4*)&As[kk][ty * 8];      // 4 distinct addrs/wave: conflict-free
      float4 a1 = *(const float4*)&As[kk][ty * 8 + 4];
      float4 bv4 = *(const float4*)&Bs[kk][tx * 4];     // 16 addrs over 256B: 2-way (free)
      float av[8] = {a0.x, a0.y, a0.z, a0.w, a1.x, a1.y, a1.z, a1.w};
      float bv[4] = {bv4.x, bv4.y, bv4.z, bv4.w};
      #pragma unroll
      for (int i = 0; i < 8; ++i)
        #pragma unroll
        for (int j = 0; j < 4; ++j) acc[i][j] += av[i] * bv[j];
    }
  }
  #pragma unroll
  for (int i = 0; i < 8; ++i) {
    float4 v = make_float4(acc[i][0], acc[i][1], acc[i][2], acc[i][3]);
    *(float4*)&G[(u64)(p0 + ty * 8 + i) * NPIXP + q0 + tx * 4] = v;
  }
}

// ---------------- fused stencil + argmax ----------------
__launch_bounds__(256)
__global__ void scoremax_kernel(const float* __restrict__ G, const float* __restrict__ rknorm,
                                u64* __restrict__ rmax, int b) {
  int y = blockIdx.x, ys = blockIdx.y;
  __shared__ float Gt[3][50][50];
  __shared__ float sc[48][48];
  __shared__ float rkl[48];
  int tid = threadIdx.x;
  for (int t = tid; t < 7500; t += 256) {
    int dy = t / 2500, rem = t % 2500;
    int u = rem / 50, v = rem - u * 50;
    Gt[dy][u][v] = G[(u64)((y + dy) * 50 + u) * NPIXP + (ys + dy) * 50 + v];
  }
  if (tid < 48) rkl[tid] = rknorm[b * HW + ys * 48 + tid];
  __syncthreads();
  #pragma unroll
  for (int k = 0; k < 9; ++k) {
    int idx = tid + k * 256;
    int x = idx / 48, xs = idx - x * 48;
    float v = 0.0f;
    #pragma unroll
    for (int dy = 0; dy < 3; ++dy)
      #pragma unroll
      for (int dx = 0; dx < 3; ++dx)
        v += Gt[dy][x + dx][xs + dx];
    sc[x][xs] = v * rkl[xs];
  }
  __syncthreads();
  if (tid < 48) {
    float best = -1e30f; int bxs = 0;
    for (int xs = 0; xs < 48; ++xs) {
      float v = sc[tid][xs];
      if (v > best) { best = v; bxs = xs; }   // strict >: smallest xs on ties
    }
    int ps = ys * 48 + bxs;
    unsigned ub = __float_as_uint(best);
    unsigned enc = (ub & 0x80000000u) ? ~ub : (ub | 0x80000000u);
    u64 key = ((u64)enc << 32) | (u64)(2303 - ps);
    atomicMax(&rmax[(u64)b * HW + y * 48 + tid], key);
  }
}

// ---------------- reassemble: paste chosen patches + overlap normalize ----------------
__global__ void reassemble_kernel(const float* __restrict__ padS_cl, const u64* __restrict__ rmax,
                                  float* __restrict__ rF_cl) {
  int pix = blockIdx.x, b = blockIdx.y;
  int y = pix / 48, x = pix % 48;
  const u64* rm = rmax + (u64)b * HW;
  const float* S = padS_cl + (u64)b * (NPIX * NC);
  int ch = threadIdx.x;
  float sum = 0.0f;
  #pragma unroll
  for (int i = 0; i < 3; ++i)
    #pragma unroll
    for (int j = 0; j < 3; ++j) {
      int yn = y + 1 - i, xn = x + 1 - j;
      if (yn >= 0 && yn < 48 && xn >= 0 && xn < 48) {
        int ps = 2303 - (int)(unsigned)(rm[yn * 48 + xn] & 0xFFFFFFFFu);
        int ys = ps / 48, xs = ps % 48;
        sum += S[((ys + i) * 50 + xs + j) * NC + ch];
      }
    }
  float cy = (y == 0 || y == 47) ? 2.0f : 3.0f;
  float cx = (x == 0 || x == 47) ? 2.0f : 3.0f;
  rF_cl[(u64)b * (HW * NC) + pix * NC + ch] = sum / (cy * cx);
}

// ---------------- coloring: out = sqrt(s)*Yf*rF + mean_s ----------------
__launch_bounds__(256)
__global__ void coloring_kernel(const float* __restrict__ Yf, const double* __restrict__ snorm,
                                const double* __restrict__ mean, const float* __restrict__ rF_cl,
                                float* __restrict__ out) {
  int b = blockIdx.z;
  const float* A = Yf + (2 + b) * MATSZ;
  const float* Bp = rF_cl + (u64)b * (HW * NC);
  const double* mn = mean + (2 + b) * NC;
  float cscale = (float)sqrt(snorm[2 + b]);
  int m0 = blockIdx.y * 32, n0 = blockIdx.x * 64;
  __shared__ float As[32][33];
  __shared__ float Bs[32][65];
  int tx = threadIdx.x, ty = threadIdx.y;
  int tid = ty * 16 + tx;
  float acc[2][4] = {};
  for (int k0 = 0; k0 < 256; k0 += 32) {
    __syncthreads();
    #pragma unroll
    for (int l = 0; l < 4; ++l) {
      int idx = tid + l * 256;
      int r = idx >> 5, cc = idx & 31;
      As[r][cc] = A[(m0 + r) * NC + k0 + cc];
    }
    #pragma unroll
    for (int l = 0; l < 8; ++l) {
      int idx = tid + l * 256;
      int kk = idx & 31, nn = idx >> 5;
      Bs[kk][nn] = Bp[(u64)(n0 + nn) * NC + k0 + kk];
    }
    __syncthreads();
    #pragma unroll
    for (int kk = 0; kk < 32; ++kk) {
      float a0 = As[ty][kk], a1 = As[ty + 16][kk];
      float b0 = Bs[kk][tx], b1 = Bs[kk][tx + 16], b2 = Bs[kk][tx + 32], b3 = Bs[kk][tx + 48];
      acc[0][0] += a0 * b0; acc[0][1] += a0 * b1; acc[0][2] += a0 * b2; acc[0][3] += a0 * b3;
      acc[1][0] += a1 * b0; acc[1][1] += a1 * b1; acc[1][2] += a1 * b2; acc[1][3] += a1 * b3;
    }
  }
  #pragma unroll
  for (int i = 0; i < 2; ++i) {
    int row = m0 + ty + 16 * i;
    float madd = (float)mn[row];
    #pragma unroll
    for (int j = 0; j < 4; ++j) {
      int n = n0 + tx + 16 * j;
      out[(u64)b * (NC * HW) + row * HW + n] = acc[i][j] * cscale + madd;
    }
  }
}

// ---------------- host ----------------
extern "C" void kernel_launch(void* const* d_in, const int* in_sizes, int n_in,
                              void* d_out, int out_size, void* d_ws, size_t ws_size,
                              hipStream_t stream) {
  const float* c = (const float*)d_in[0];
  const float* s = (const float*)d_in[1];
  float* out = (float*)d_out;

  char* ws = (char*)d_ws;
  size_t off = 0;
  auto alloc = [&](size_t bytes) {
    void* p = ws + off;
    off = (off + bytes + 255) & ~(size_t)255;
    return p;
  };
  double* mean   = (double*)alloc(4 * NC * sizeof(double));
  float* cov     = (float*)alloc((size_t)4 * MATSZ * sizeof(float));
  float* covp    = (float*)alloc((size_t)4 * NSLAB * MATSZ * sizeof(float));
  float* Ya      = (float*)alloc((size_t)4 * MATSZ * sizeof(float));
  float* Yb      = (float*)alloc((size_t)4 * MATSZ * sizeof(float));
  float* Za      = (float*)alloc((size_t)4 * MATSZ * sizeof(float));
  float* Zb      = (float*)alloc((size_t)4 * MATSZ * sizeof(float));
  float* T       = (float*)alloc((size_t)4 * MATSZ * sizeof(float));
  float* padC_cf = (float*)alloc((size_t)2 * NC * NPIXP * sizeof(float));
  float* padS_cf = (float*)alloc((size_t)2 * NC * NPIXP * sizeof(float));
  float* padS_cl = (float*)alloc((size_t)2 * NPIX * NC * sizeof(float));
  float* rknorm  = (float*)alloc((size_t)2 * HW * sizeof(float));
  float* rF_cl   = (float*)alloc((size_t)2 * HW * NC * sizeof(float));
  float* G       = (float*)alloc((size_t)NPIXP * NPIXP * sizeof(float)); // per-batch Gram
  u64*   rmax    = (u64*)alloc((size_t)2 * HW * sizeof(u64));
  double* snorm  = (double*)alloc(4 * sizeof(double));

  size_t padBytes = (size_t)(2 * NC * NPIXP + 2 * NC * NPIXP + 2 * NPIX * NC) * sizeof(float);
  hipMemsetAsync(padC_cf, 0, padBytes, stream);
  hipMemsetAsync(rmax, 0, (size_t)2 * HW * sizeof(u64) + 4 * sizeof(double), stream);

  mean_kernel<<<dim3(256, 4), 64, 0, stream>>>(c, s, mean);
  cov_part<<<dim3(4, 4, 4 * NSLAB), dim3(16, 16), 0, stream>>>(c, s, covp);
  cov_reduce<<<dim3(256, 4), 256, 0, stream>>>(covp, mean, cov, snorm);
  ns_init<<<dim3(256, 4), 256, 0, stream>>>(cov, snorm, Ya, Za);

  float *Yc = Ya, *Zc = Za, *Yn = Yb, *Zn = Zb;
  for (int it = 0; it < NS_ITERS; ++it) {
    ns_gemm_T<<<dim3(8, 8, 4), dim3(16, 16), 0, stream>>>(Zc, Yc, T);
    ns_gemm_YZ<<<dim3(8, 8, 8), dim3(16, 16), 0, stream>>>(Yc, Zc, T, Yn, Zn);
    float* t1 = Yc; Yc = Yn; Yn = t1;
    float* t2 = Zc; Zc = Zn; Zn = t2;
  }

  whiten_kernel<<<dim3(36, 8, 4), dim3(16, 16), 0, stream>>>(c, s, Zc, snorm, mean,
                                                             padC_cf, padS_cf, padS_cl);
  knorm_kernel<<<dim3(2304, 2), 256, 0, stream>>>(padS_cl, rknorm);

  for (int b = 0; b < 2; ++b) {
    gram_gemm<<<dim3(20, 40), dim3(16, 16), 0, stream>>>(padC_cf, padS_cf, G, b);
    scoremax_kernel<<<dim3(48, 48), 256, 0, stream>>>(G, rknorm, rmax, b);
  }

  reassemble_kernel<<<dim3(2304, 2), 256, 0, stream>>>(padS_cl, rmax, rF_cl);
  coloring_kernel<<<dim3(36, 8, 2), dim3(16, 16), 0, stream>>>(Yc, snorm, mean, rF_cl, out);
}

// Round 10
// 374.607 us; speedup vs baseline: 2.6746x; 1.1638x over previous
//
#include <hip/hip_runtime.h>
#include <math.h>

#define HW 2304       // 48*48
#define NC 256        // channels
#define NPIX 2500     // 50*50 padded grid (channel-last buffer)
#define NPIXP 2560    // padded row stride for channel-first buffers / Gram
#define MATSZ 65536   // 256*256
#define NS_ITERS 5    // e5 ~ 7e-9 from e0=0.644; f32-converged
#define NSLAB 6
#define KSLAB 384     // 2304/6
#define PMSZ (2560 * 256)  // pixel-major buffer elems per batch

typedef unsigned long long u64;
typedef unsigned short ushortt;
typedef __attribute__((ext_vector_type(8))) short bhalf8;
typedef __attribute__((ext_vector_type(4))) float f32x4;

// ---------------- means (f64) ----------------
__global__ void mean_kernel(const float* __restrict__ c, const float* __restrict__ s,
                            double* __restrict__ mean) {
  int ch = blockIdx.x, m = blockIdx.y;
  const float* src = (m < 2 ? c + m * (NC * HW) : s + (m - 2) * (NC * HW)) + ch * HW;
  double acc = 0.0;
  for (int n = threadIdx.x; n < HW; n += 64) acc += (double)src[n];
  for (int o = 32; o > 0; o >>= 1) acc += __shfl_down(acc, o);
  if (threadIdx.x == 0) mean[m * NC + ch] = acc / (double)HW;
}

// ---------------- covariance partials: raw sum(x*y), 64x64 tile, 4x4/thread ----------------
__launch_bounds__(256)
__global__ void cov_part(const float* __restrict__ c, const float* __restrict__ s,
                         float* __restrict__ covp) {
  int z = blockIdx.z;
  int m = z / NSLAB, slab = z % NSLAB;
  const float* src = (m < 2 ? c + m * (NC * HW) : s + (m - 2) * (NC * HW));
  int i0 = blockIdx.y * 64, j0 = blockIdx.x * 64;
  int kb = slab * KSLAB;
  __shared__ float As[16][64], Bs[16][64];
  int tx = threadIdx.x, ty = threadIdx.y;
  int tid = ty * 16 + tx;
  int li = tid >> 2;
  int lk4 = tid & 3;
  float acc[4][4] = {};
  for (int kc = 0; kc < KSLAB; kc += 16) {
    __syncthreads();
    float4 va = *(const float4*)&src[(u64)(i0 + li) * HW + kb + kc + lk4 * 4];
    float4 vb = *(const float4*)&src[(u64)(j0 + li) * HW + kb + kc + lk4 * 4];
    As[lk4 * 4 + 0][li] = va.x; As[lk4 * 4 + 1][li] = va.y;
    As[lk4 * 4 + 2][li] = va.z; As[lk4 * 4 + 3][li] = va.w;
    Bs[lk4 * 4 + 0][li] = vb.x; Bs[lk4 * 4 + 1][li] = vb.y;
    Bs[lk4 * 4 + 2][li] = vb.z; Bs[lk4 * 4 + 3][li] = vb.w;
    __syncthreads();
    #pragma unroll
    for (int kk = 0; kk < 16; ++kk) {
      float4 a = *(const float4*)&As[kk][ty * 4];
      float4 b = *(const float4*)&Bs[kk][tx * 4];
      float av[4] = {a.x, a.y, a.z, a.w};
      float bv[4] = {b.x, b.y, b.z, b.w};
      #pragma unroll
      for (int i = 0; i < 4; ++i)
        #pragma unroll
        for (int j = 0; j < 4; ++j) acc[i][j] += av[i] * bv[j];
    }
  }
  float* Cp = covp + (u64)z * MATSZ;
  #pragma unroll
  for (int i = 0; i < 4; ++i) {
    float4 v = make_float4(acc[i][0], acc[i][1], acc[i][2], acc[i][3]);
    *(float4*)&Cp[(i0 + ty * 4 + i) * NC + j0 + tx * 4] = v;
  }
}

// grid(256,4), block 256: cov = sum(slabs) - HW*mu_i*mu_j; diag -> snorm (trace fused)
__global__ void cov_reduce(const float* __restrict__ covp, const double* __restrict__ mean,
                           float* __restrict__ cov, double* __restrict__ snorm) {
  int m = blockIdx.y;
  int row = blockIdx.x, col = threadIdx.x;
  int e = row * 256 + col;
  float v = 0.0f;
  #pragma unroll
  for (int slab = 0; slab < NSLAB; ++slab)
    v += covp[(u64)(m * NSLAB + slab) * MATSZ + e];
  double mi = mean[m * NC + row], mj = mean[m * NC + col];
  float res = (float)((double)v - (double)HW * mi * mj);
  cov[m * MATSZ + e] = res;
  if (col == row) atomicAdd(&snorm[m], 1.25 * (double)res / 256.0);
}

__global__ void ns_init(const float* __restrict__ cov, const double* __restrict__ snorm,
                        float* __restrict__ Y, float* __restrict__ Z) {
  int m = blockIdx.y;
  int e = blockIdx.x * 256 + threadIdx.x;
  double inv = 1.0 / snorm[m];
  Y[m * MATSZ + e] = (float)((double)cov[m * MATSZ + e] * inv);
  Z[m * MATSZ + e] = ((e >> 8) == (e & 255)) ? 1.0f : 0.0f;
}

// ---------------- Newton-Schulz GEMMs (256x256x256, f32) ----------------
__launch_bounds__(256)
__global__ void ns_gemm_T(const float* __restrict__ Zc, const float* __restrict__ Yc,
                          float* __restrict__ T) {
  int m = blockIdx.z;
  const float* A = Zc + m * MATSZ;
  const float* B = Yc + m * MATSZ;
  int m0 = blockIdx.y * 32, n0 = blockIdx.x * 32;
  __shared__ float As[32][33], Bs[32][33];
  int tx = threadIdx.x, ty = threadIdx.y;
  int tid = ty * 16 + tx;
  float acc[2][2] = {};
  for (int k0 = 0; k0 < 256; k0 += 32) {
    __syncthreads();
    #pragma unroll
    for (int l = 0; l < 4; ++l) {
      int idx = tid + l * 256;
      int r = idx >> 5, cc = idx & 31;
      As[r][cc] = A[(m0 + r) * NC + k0 + cc];
      Bs[r][cc] = B[(k0 + r) * NC + n0 + cc];
    }
    __syncthreads();
    #pragma unroll
    for (int kk = 0; kk < 32; ++kk) {
      float a0 = As[ty][kk], a1 = As[ty + 16][kk];
      float b0 = Bs[kk][tx], b1 = Bs[kk][tx + 16];
      acc[0][0] += a0 * b0; acc[0][1] += a0 * b1;
      acc[1][0] += a1 * b0; acc[1][1] += a1 * b1;
    }
  }
  float* Cp = T + m * MATSZ;
  #pragma unroll
  for (int i = 0; i < 2; ++i)
    #pragma unroll
    for (int j = 0; j < 2; ++j) {
      int row = m0 + ty + 16 * i, col = n0 + tx + 16 * j;
      Cp[row * NC + col] = (row == col ? 1.5f : 0.0f) - 0.5f * acc[i][j];
    }
}

__launch_bounds__(256)
__global__ void ns_gemm_YZ(const float* __restrict__ Yc, const float* __restrict__ Zc,
                           const float* __restrict__ T,
                           float* __restrict__ Yn, float* __restrict__ Zn) {
  int z = blockIdx.z;
  int m = z & 3;
  bool isY = (z < 4);
  const float* A = isY ? (Yc + m * MATSZ) : (T + m * MATSZ);
  const float* B = isY ? (T + m * MATSZ) : (Zc + m * MATSZ);
  float* Cp = isY ? (Yn + m * MATSZ) : (Zn + m * MATSZ);
  int m0 = blockIdx.y * 32, n0 = blockIdx.x * 32;
  __shared__ float As[32][33], Bs[32][33];
  int tx = threadIdx.x, ty = threadIdx.y;
  int tid = ty * 16 + tx;
  float acc[2][2] = {};
  for (int k0 = 0; k0 < 256; k0 += 32) {
    __syncthreads();
    #pragma unroll
    for (int l = 0; l < 4; ++l) {
      int idx = tid + l * 256;
      int r = idx >> 5, cc = idx & 31;
      As[r][cc] = A[(m0 + r) * NC + k0 + cc];
      Bs[r][cc] = B[(k0 + r) * NC + n0 + cc];
    }
    __syncthreads();
    #pragma unroll
    for (int kk = 0; kk < 32; ++kk) {
      float a0 = As[ty][kk], a1 = As[ty + 16][kk];
      float b0 = Bs[kk][tx], b1 = Bs[kk][tx + 16];
      acc[0][0] += a0 * b0; acc[0][1] += a0 * b1;
      acc[1][0] += a1 * b0; acc[1][1] += a1 * b1;
    }
  }
  #pragma unroll
  for (int i = 0; i < 2; ++i)
    #pragma unroll
    for (int j = 0; j < 2; ++j)
      Cp[(m0 + ty + 16 * i) * NC + n0 + tx + 16 * j] = acc[i][j];
}

// ---------------- whitening apply -> padded norm buffers ----------------
__launch_bounds__(256)
__global__ void whiten_kernel(const float* __restrict__ c, const float* __restrict__ s,
                              const float* __restrict__ Zf,
                              const double* __restrict__ snorm, const double* __restrict__ mean,
                              float* __restrict__ padC_cf, float* __restrict__ padS_cf,
                              float* __restrict__ padS_cl) {
  int mat = blockIdx.z;
  const float* src = (mat < 2 ? c + mat * (NC * HW) : s + (mat - 2) * (NC * HW));
  const float* A = Zf + mat * MATSZ;
  const double* mn = mean + mat * NC;
  float wscale = (float)(1.0 / sqrt(snorm[mat]));
  int m0 = blockIdx.y * 32, n0 = blockIdx.x * 64;
  __shared__ float As[32][33];
  __shared__ float Bs[32][65];
  int tx = threadIdx.x, ty = threadIdx.y;
  int tid = ty * 16 + tx;
  float acc[2][4] = {};
  for (int k0 = 0; k0 < 256; k0 += 32) {
    __syncthreads();
    #pragma unroll
    for (int l = 0; l < 4; ++l) {
      int idx = tid + l * 256;
      int r = idx >> 5, cc = idx & 31;
      As[r][cc] = A[(m0 + r) * NC + k0 + cc];
    }
    #pragma unroll
    for (int l = 0; l < 8; ++l) {
      int idx = tid + l * 256;
      int kk = idx >> 6, nn = idx & 63;
      Bs[kk][nn] = src[(k0 + kk) * HW + n0 + nn] - (float)mn[k0 + kk];
    }
    __syncthreads();
    #pragma unroll
    for (int kk = 0; kk < 32; ++kk) {
      float a0 = As[ty][kk], a1 = As[ty + 16][kk];
      float b0 = Bs[kk][tx], b1 = Bs[kk][tx + 16], b2 = Bs[kk][tx + 32], b3 = Bs[kk][tx + 48];
      acc[0][0] += a0 * b0; acc[0][1] += a0 * b1; acc[0][2] += a0 * b2; acc[0][3] += a0 * b3;
      acc[1][0] += a1 * b0; acc[1][1] += a1 * b1; acc[1][2] += a1 * b2; acc[1][3] += a1 * b3;
    }
  }
  #pragma unroll
  for (int i = 0; i < 2; ++i) {
    int row = m0 + ty + 16 * i;
    #pragma unroll
    for (int j = 0; j < 4; ++j) {
      int n = n0 + tx + 16 * j;
      float v = acc[i][j] * wscale;
      int y = n / 48, x = n % 48;
      int ppos = (y + 1) * 50 + (x + 1);
      if (mat < 2) {
        padC_cf[(u64)mat * (NC * NPIXP) + row * NPIXP + ppos] = v;
      } else {
        padS_cf[(u64)(mat - 2) * (NC * NPIXP) + row * NPIXP + ppos] = v;
        padS_cl[(u64)(mat - 2) * (NPIX * NC) + ppos * NC + row] = v;
      }
    }
  }
}

// ---------------- transpose + bf16 split: cf [k][p] f32 -> pixel-major [p][k] bf16 hi/lo ----
// grid(40, 4), block 256. Per block: 64 pixels x 256 channels.
__launch_bounds__(256)
__global__ void tsplit_kernel(const float* __restrict__ padC_cf, const float* __restrict__ padS_cf,
                              ushortt* __restrict__ padCk_hi, ushortt* __restrict__ padCk_lo,
                              ushortt* __restrict__ padSk_hi, ushortt* __restrict__ padSk_lo) {
  int p0 = blockIdx.x * 64;
  int by = blockIdx.y;
  const float* src = (by < 2) ? padC_cf + (u64)by * (NC * NPIXP)
                              : padS_cf + (u64)(by - 2) * (NC * NPIXP);
  ushortt* dhi = (by < 2) ? padCk_hi + (u64)by * PMSZ : padSk_hi + (u64)(by - 2) * PMSZ;
  ushortt* dlo = (by < 2) ? padCk_lo + (u64)by * PMSZ : padSk_lo + (u64)(by - 2) * PMSZ;
  __shared__ float Tk[64][68];
  int tid = threadIdx.x;
  int rr = tid >> 4, c4 = (tid & 15) * 4;
  int p = tid >> 2, kg = (tid & 3) * 16;
  for (int ks = 0; ks < 256; ks += 64) {
    __syncthreads();
    #pragma unroll
    for (int it = 0; it < 4; ++it) {
      int r = rr + it * 16;
      *(float4*)&Tk[r][c4] = *(const float4*)&src[(u64)(ks + r) * NPIXP + p0 + c4];
    }
    __syncthreads();
    __align__(16) ushortt h[16], lo[16];
    #pragma unroll
    for (int e = 0; e < 16; ++e) {
      float v = Tk[kg + e][p];
      unsigned bb = __float_as_uint(v);
      unsigned hu = (bb + 0x7FFFu + ((bb >> 16) & 1u)) >> 16;
      float hf = __uint_as_float(hu << 16);
      float rres = v - hf;
      unsigned lb = __float_as_uint(rres);
      unsigned lu = (lb + 0x7FFFu + ((lb >> 16) & 1u)) >> 16;
      h[e] = (ushortt)hu;
      lo[e] = (ushortt)lu;
    }
    u64 off = (u64)(p0 + p) * 256 + ks + kg;
    *(uint4*)&dhi[off] = *(const uint4*)&h[0];
    *(uint4*)&dhi[off + 8] = *(const uint4*)&h[8];
    *(uint4*)&dlo[off] = *(const uint4*)&lo[0];
    *(uint4*)&dlo[off + 8] = *(const uint4*)&lo[8];
  }
}

// ---------------- patch norms: rknorm = 1/||ker(ps)|| ----------------
__global__ void knorm_kernel(const float* __restrict__ padS_cl, float* __restrict__ rknorm) {
  int ps = blockIdx.x, b = blockIdx.y;
  int ys = ps / 48, xs = ps % 48;
  const float* S = padS_cl + (u64)b * (NPIX * NC);
  int ch = threadIdx.x;
  double acc = 0.0;
  #pragma unroll
  for (int dy = 0; dy < 3; ++dy)
    #pragma unroll
    for (int dx = 0; dx < 3; ++dx) {
      float v = S[((ys + dy) * 50 + xs + dx) * NC + ch];
      acc += (double)v * (double)v;
    }
  __shared__ double sd[256];
  int t = threadIdx.x;
  sd[t] = acc; __syncthreads();
  for (int st = 128; st > 0; st >>= 1) {
    if (t < st) sd[t] += sd[t + st];
    __syncthreads();
  }
  if (ch == 0) rknorm[b * HW + ps] = (float)(1.0 / sqrt(sd[0]));
}

// ---------------- MFMA Gram: G[p][q] = sum_k C[p][k]*S[q][k], split-bf16 (hh+hl+lh) --------
// tile 128x64, 4 waves, BK=32. grid(20,40), block 256.
__launch_bounds__(256)
__global__ void gram_mfma(const ushortt* __restrict__ Ah_g, const ushortt* __restrict__ Al_g,
                          const ushortt* __restrict__ Bh_g, const ushortt* __restrict__ Bl_g,
                          float* __restrict__ G) {
  __shared__ ushortt As_hi[128 * 32], As_lo[128 * 32], Bs_hi[64 * 32], Bs_lo[64 * 32];
  int tid = threadIdx.x;
  int wv = tid >> 6, l = tid & 63, lr = l & 15, lk = l >> 4;
  int p0 = blockIdx.x * 128, q0 = blockIdx.y * 64;
  int arow = tid >> 2;              // 0..63
  int apart = (tid & 3) * 8;        // ushort offset (16B granules)
  const ushortt* pAh0 = Ah_g + (u64)(p0 + arow) * 256 + apart;
  const ushortt* pAh1 = Ah_g + (u64)(p0 + arow + 64) * 256 + apart;
  const ushortt* pAl0 = Al_g + (u64)(p0 + arow) * 256 + apart;
  const ushortt* pAl1 = Al_g + (u64)(p0 + arow + 64) * 256 + apart;
  const ushortt* pBh  = Bh_g + (u64)(q0 + arow) * 256 + apart;
  const ushortt* pBl  = Bl_g + (u64)(q0 + arow) * 256 + apart;
  // prefetch chunk 0
  float4 rAh0 = *(const float4*)pAh0;
  float4 rAh1 = *(const float4*)pAh1;
  float4 rAl0 = *(const float4*)pAl0;
  float4 rAl1 = *(const float4*)pAl1;
  float4 rBh  = *(const float4*)pBh;
  float4 rBl  = *(const float4*)pBl;
  f32x4 acc[2][4];
  #pragma unroll
  for (int a = 0; a < 2; ++a)
    #pragma unroll
    for (int b = 0; b < 4; ++b)
      #pragma unroll
      for (int e = 0; e < 4; ++e) acc[a][b][e] = 0.0f;
  for (int k0 = 0; k0 < 256; k0 += 32) {
    __syncthreads();
    *(float4*)&As_hi[arow * 32 + apart] = rAh0;
    *(float4*)&As_hi[(arow + 64) * 32 + apart] = rAh1;
    *(float4*)&As_lo[arow * 32 + apart] = rAl0;
    *(float4*)&As_lo[(arow + 64) * 32 + apart] = rAl1;
    *(float4*)&Bs_hi[arow * 32 + apart] = rBh;
    *(float4*)&Bs_lo[arow * 32 + apart] = rBl;
    __syncthreads();
    if (k0 + 32 < 256) {
      rAh0 = *(const float4*)(pAh0 + k0 + 32);
      rAh1 = *(const float4*)(pAh1 + k0 + 32);
      rAl0 = *(const float4*)(pAl0 + k0 + 32);
      rAl1 = *(const float4*)(pAl1 + k0 + 32);
      rBh  = *(const float4*)(pBh + k0 + 32);
      rBl  = *(const float4*)(pBl + k0 + 32);
    }
    bhalf8 Ah[2], Al[2], Bh[4], Bl[4];
    #pragma unroll
    for (int a = 0; a < 2; ++a) {
      int off = (wv * 32 + a * 16 + lr) * 32 + lk * 8;
      Ah[a] = *(const bhalf8*)&As_hi[off];
      Al[a] = *(const bhalf8*)&As_lo[off];
    }
    #pragma unroll
    for (int b = 0; b < 4; ++b) {
      int off = (b * 16 + lr) * 32 + lk * 8;
      Bh[b] = *(const bhalf8*)&Bs_hi[off];
      Bl[b] = *(const bhalf8*)&Bs_lo[off];
    }
    #pragma unroll
    for (int a = 0; a < 2; ++a)
      #pragma unroll
      for (int b = 0; b < 4; ++b) {
        acc[a][b] = __builtin_amdgcn_mfma_f32_16x16x32_bf16(Ah[a], Bh[b], acc[a][b], 0, 0, 0);
        acc[a][b] = __builtin_amdgcn_mfma_f32_16x16x32_bf16(Ah[a], Bl[b], acc[a][b], 0, 0, 0);
        acc[a][b] = __builtin_amdgcn_mfma_f32_16x16x32_bf16(Al[a], Bh[b], acc[a][b], 0, 0, 0);
      }
  }
  // C/D layout: col = lane&15, row = (lane>>4)*4 + reg
  #pragma unroll
  for (int a = 0; a < 2; ++a)
    #pragma unroll
    for (int b = 0; b < 4; ++b)
      #pragma unroll
      for (int r = 0; r < 4; ++r) {
        int p = p0 + wv * 32 + a * 16 + lk * 4 + r;
        int q = q0 + b * 16 + lr;
        G[(u64)p * NPIXP + q] = acc[a][b][r];
      }
}

// ---------------- fused stencil + argmax ----------------
__launch_bounds__(256)
__global__ void scoremax_kernel(const float* __restrict__ G, const float* __restrict__ rknorm,
                                u64* __restrict__ rmax, int b) {
  int y = blockIdx.x, ys = blockIdx.y;
  __shared__ float Gt[3][50][50];
  __shared__ float sc[48][48];
  __shared__ float rkl[48];
  int tid = threadIdx.x;
  for (int t = tid; t < 7500; t += 256) {
    int dy = t / 2500, rem = t % 2500;
    int u = rem / 50, v = rem - u * 50;
    Gt[dy][u][v] = G[(u64)((y + dy) * 50 + u) * NPIXP + (ys + dy) * 50 + v];
  }
  if (tid < 48) rkl[tid] = rknorm[b * HW + ys * 48 + tid];
  __syncthreads();
  #pragma unroll
  for (int k = 0; k < 9; ++k) {
    int idx = tid + k * 256;
    int x = idx / 48, xs = idx - x * 48;
    float v = 0.0f;
    #pragma unroll
    for (int dy = 0; dy < 3; ++dy)
      #pragma unroll
      for (int dx = 0; dx < 3; ++dx)
        v += Gt[dy][x + dx][xs + dx];
    sc[x][xs] = v * rkl[xs];
  }
  __syncthreads();
  if (tid < 48) {
    float best = -1e30f; int bxs = 0;
    for (int xs = 0; xs < 48; ++xs) {
      float v = sc[tid][xs];
      if (v > best) { best = v; bxs = xs; }   // strict >: smallest xs on ties
    }
    int ps = ys * 48 + bxs;
    unsigned ub = __float_as_uint(best);
    unsigned enc = (ub & 0x80000000u) ? ~ub : (ub | 0x80000000u);
    u64 key = ((u64)enc << 32) | (u64)(2303 - ps);
    atomicMax(&rmax[(u64)b * HW + y * 48 + tid], key);
  }
}

// ---------------- reassemble: paste chosen patches + overlap normalize ----------------
__global__ void reassemble_kernel(const float* __restrict__ padS_cl, const u64* __restrict__ rmax,
                                  float* __restrict__ rF_cl) {
  int pix = blockIdx.x, b = blockIdx.y;
  int y = pix / 48, x = pix % 48;
  const u64* rm = rmax + (u64)b * HW;
  const float* S = padS_cl + (u64)b * (NPIX * NC);
  int ch = threadIdx.x;
  float sum = 0.0f;
  #pragma unroll
  for (int i = 0; i < 3; ++i)
    #pragma unroll
    for (int j = 0; j < 3; ++j) {
      int yn = y + 1 - i, xn = x + 1 - j;
      if (yn >= 0 && yn < 48 && xn >= 0 && xn < 48) {
        int ps = 2303 - (int)(unsigned)(rm[yn * 48 + xn] & 0xFFFFFFFFu);
        int ys = ps / 48, xs = ps % 48;
        sum += S[((ys + i) * 50 + xs + j) * NC + ch];
      }
    }
  float cy = (y == 0 || y == 47) ? 2.0f : 3.0f;
  float cx = (x == 0 || x == 47) ? 2.0f : 3.0f;
  rF_cl[(u64)b * (HW * NC) + pix * NC + ch] = sum / (cy * cx);
}

// ---------------- coloring: out = sqrt(s)*Yf*rF + mean_s ----------------
__launch_bounds__(256)
__global__ void coloring_kernel(const float* __restrict__ Yf, const double* __restrict__ snorm,
                                const double* __restrict__ mean, const float* __restrict__ rF_cl,
                                float* __restrict__ out) {
  int b = blockIdx.z;
  const float* A = Yf + (2 + b) * MATSZ;
  const float* Bp = rF_cl + (u64)b * (HW * NC);
  const double* mn = mean + (2 + b) * NC;
  float cscale = (float)sqrt(snorm[2 + b]);
  int m0 = blockIdx.y * 32, n0 = blockIdx.x * 64;
  __shared__ float As[32][33];
  __shared__ float Bs[32][65];
  int tx = threadIdx.x, ty = threadIdx.y;
  int tid = ty * 16 + tx;
  float acc[2][4] = {};
  for (int k0 = 0; k0 < 256; k0 += 32) {
    __syncthreads();
    #pragma unroll
    for (int l = 0; l < 4; ++l) {
      int idx = tid + l * 256;
      int r = idx >> 5, cc = idx & 31;
      As[r][cc] = A[(m0 + r) * NC + k0 + cc];
    }
    #pragma unroll
    for (int l = 0; l < 8; ++l) {
      int idx = tid + l * 256;
      int kk = idx & 31, nn = idx >> 5;
      Bs[kk][nn] = Bp[(u64)(n0 + nn) * NC + k0 + kk];
    }
    __syncthreads();
    #pragma unroll
    for (int kk = 0; kk < 32; ++kk) {
      float a0 = As[ty][kk], a1 = As[ty + 16][kk];
      float b0 = Bs[kk][tx], b1 = Bs[kk][tx + 16], b2 = Bs[kk][tx + 32], b3 = Bs[kk][tx + 48];
      acc[0][0] += a0 * b0; acc[0][1] += a0 * b1; acc[0][2] += a0 * b2; acc[0][3] += a0 * b3;
      acc[1][0] += a1 * b0; acc[1][1] += a1 * b1; acc[1][2] += a1 * b2; acc[1][3] += a1 * b3;
    }
  }
  #pragma unroll
  for (int i = 0; i < 2; ++i) {
    int row = m0 + ty + 16 * i;
    float madd = (float)mn[row];
    #pragma unroll
    for (int j = 0; j < 4; ++j) {
      int n = n0 + tx + 16 * j;
      out[(u64)b * (NC * HW) + row * HW + n] = acc[i][j] * cscale + madd;
    }
  }
}

// ---------------- host ----------------
extern "C" void kernel_launch(void* const* d_in, const int* in_sizes, int n_in,
                              void* d_out, int out_size, void* d_ws, size_t ws_size,
                              hipStream_t stream) {
  const float* c = (const float*)d_in[0];
  const float* s = (const float*)d_in[1];
  float* out = (float*)d_out;

  char* ws = (char*)d_ws;
  size_t off = 0;
  auto alloc = [&](size_t bytes) {
    void* p = ws + off;
    off = (off + bytes + 255) & ~(size_t)255;
    return p;
  };
  double* mean   = (double*)alloc(4 * NC * sizeof(double));
  float* cov     = (float*)alloc((size_t)4 * MATSZ * sizeof(float));
  float* covp    = (float*)alloc((size_t)4 * NSLAB * MATSZ * sizeof(float));
  float* Ya      = (float*)alloc((size_t)4 * MATSZ * sizeof(float));
  float* Yb      = (float*)alloc((size_t)4 * MATSZ * sizeof(float));
  float* Za      = (float*)alloc((size_t)4 * MATSZ * sizeof(float));
  float* Zb      = (float*)alloc((size_t)4 * MATSZ * sizeof(float));
  float* T       = (float*)alloc((size_t)4 * MATSZ * sizeof(float));
  // pads: three consecutive allocs -> one memset
  float* padC_cf = (float*)alloc((size_t)2 * NC * NPIXP * sizeof(float));
  float* padS_cf = (float*)alloc((size_t)2 * NC * NPIXP * sizeof(float));
  float* padS_cl = (float*)alloc((size_t)2 * NPIX * NC * sizeof(float));
  ushortt* padCk_hi = (ushortt*)alloc((size_t)2 * PMSZ * sizeof(ushortt)); // fully overwritten
  ushortt* padCk_lo = (ushortt*)alloc((size_t)2 * PMSZ * sizeof(ushortt));
  ushortt* padSk_hi = (ushortt*)alloc((size_t)2 * PMSZ * sizeof(ushortt));
  ushortt* padSk_lo = (ushortt*)alloc((size_t)2 * PMSZ * sizeof(ushortt));
  float* rknorm  = (float*)alloc((size_t)2 * HW * sizeof(float));
  float* rF_cl   = (float*)alloc((size_t)2 * HW * NC * sizeof(float));
  float* G       = (float*)alloc((size_t)NPIXP * NPIXP * sizeof(float)); // per-batch Gram
  u64*   rmax    = (u64*)alloc((size_t)2 * HW * sizeof(u64));
  double* snorm  = (double*)alloc(4 * sizeof(double));

  size_t padBytes = (size_t)(2 * NC * NPIXP + 2 * NC * NPIXP + 2 * NPIX * NC) * sizeof(float);
  hipMemsetAsync(padC_cf, 0, padBytes, stream);
  hipMemsetAsync(rmax, 0, (size_t)2 * HW * sizeof(u64) + 4 * sizeof(double), stream);

  mean_kernel<<<dim3(256, 4), 64, 0, stream>>>(c, s, mean);
  cov_part<<<dim3(4, 4, 4 * NSLAB), dim3(16, 16), 0, stream>>>(c, s, covp);
  cov_reduce<<<dim3(256, 4), 256, 0, stream>>>(covp, mean, cov, snorm);
  ns_init<<<dim3(256, 4), 256, 0, stream>>>(cov, snorm, Ya, Za);

  float *Yc = Ya, *Zc = Za, *Yn = Yb, *Zn = Zb;
  for (int it = 0; it < NS_ITERS; ++it) {
    ns_gemm_T<<<dim3(8, 8, 4), dim3(16, 16), 0, stream>>>(Zc, Yc, T);
    ns_gemm_YZ<<<dim3(8, 8, 8), dim3(16, 16), 0, stream>>>(Yc, Zc, T, Yn, Zn);
    float* t1 = Yc; Yc = Yn; Yn = t1;
    float* t2 = Zc; Zc = Zn; Zn = t2;
  }

  whiten_kernel<<<dim3(36, 8, 4), dim3(16, 16), 0, stream>>>(c, s, Zc, snorm, mean,
                                                             padC_cf, padS_cf, padS_cl);
  tsplit_kernel<<<dim3(40, 4), 256, 0, stream>>>(padC_cf, padS_cf,
                                                 padCk_hi, padCk_lo, padSk_hi, padSk_lo);
  knorm_kernel<<<dim3(2304, 2), 256, 0, stream>>>(padS_cl, rknorm);

  for (int b = 0; b < 2; ++b) {
    gram_mfma<<<dim3(20, 40), 256, 0, stream>>>(padCk_hi + (u64)b * PMSZ,
                                                padCk_lo + (u64)b * PMSZ,
                                                padSk_hi + (u64)b * PMSZ,
                                                padSk_lo + (u64)b * PMSZ, G);
    scoremax_kernel<<<dim3(48, 48), 256, 0, stream>>>(G, rknorm, rmax, b);
  }

  reassemble_kernel<<<dim3(2304, 2), 256, 0, stream>>>(padS_cl, rmax, rF_cl);
  coloring_kernel<<<dim3(36, 8, 2), dim3(16, 16), 0, stream>>>(Yc, snorm, mean, rF_cl, out);
}

// Round 11
// 359.726 us; speedup vs baseline: 2.7853x; 1.0414x over previous
//
#include <hip/hip_runtime.h>
#include <math.h>

#define HW 2304       // 48*48
#define NC 256        // channels
#define NPIX 2500     // 50*50 padded grid (channel-last buffer)
#define NPIXP 2560    // padded row stride for channel-first buffers / Gram
#define MATSZ 65536   // 256*256
#define NS_ITERS 5    // e5 ~ 7e-9 from e0=0.644; f32-converged
#define NSLAB 6
#define KSLAB 384     // 2304/6
#define PMSZ (2560 * 256)  // pixel-major buffer elems per batch

typedef unsigned long long u64;
typedef unsigned short ushortt;
typedef __attribute__((ext_vector_type(8))) short bhalf8;
typedef __attribute__((ext_vector_type(4))) float f32x4;

// ---------------- means (f64) ----------------
__global__ void mean_kernel(const float* __restrict__ c, const float* __restrict__ s,
                            double* __restrict__ mean) {
  int ch = blockIdx.x, m = blockIdx.y;
  const float* src = (m < 2 ? c + m * (NC * HW) : s + (m - 2) * (NC * HW)) + ch * HW;
  double acc = 0.0;
  for (int n = threadIdx.x; n < HW; n += 64) acc += (double)src[n];
  for (int o = 32; o > 0; o >>= 1) acc += __shfl_down(acc, o);
  if (threadIdx.x == 0) mean[m * NC + ch] = acc / (double)HW;
}

// ---------------- covariance partials: raw sum(x*y), 64x64 tile, 4x4/thread ----------------
__launch_bounds__(256)
__global__ void cov_part(const float* __restrict__ c, const float* __restrict__ s,
                         float* __restrict__ covp) {
  int z = blockIdx.z;
  int m = z / NSLAB, slab = z % NSLAB;
  const float* src = (m < 2 ? c + m * (NC * HW) : s + (m - 2) * (NC * HW));
  int i0 = blockIdx.y * 64, j0 = blockIdx.x * 64;
  int kb = slab * KSLAB;
  __shared__ float As[16][64], Bs[16][64];
  int tx = threadIdx.x, ty = threadIdx.y;
  int tid = ty * 16 + tx;
  int li = tid >> 2;
  int lk4 = tid & 3;
  float acc[4][4] = {};
  for (int kc = 0; kc < KSLAB; kc += 16) {
    __syncthreads();
    float4 va = *(const float4*)&src[(u64)(i0 + li) * HW + kb + kc + lk4 * 4];
    float4 vb = *(const float4*)&src[(u64)(j0 + li) * HW + kb + kc + lk4 * 4];
    As[lk4 * 4 + 0][li] = va.x; As[lk4 * 4 + 1][li] = va.y;
    As[lk4 * 4 + 2][li] = va.z; As[lk4 * 4 + 3][li] = va.w;
    Bs[lk4 * 4 + 0][li] = vb.x; Bs[lk4 * 4 + 1][li] = vb.y;
    Bs[lk4 * 4 + 2][li] = vb.z; Bs[lk4 * 4 + 3][li] = vb.w;
    __syncthreads();
    #pragma unroll
    for (int kk = 0; kk < 16; ++kk) {
      float4 a = *(const float4*)&As[kk][ty * 4];
      float4 b = *(const float4*)&Bs[kk][tx * 4];
      float av[4] = {a.x, a.y, a.z, a.w};
      float bv[4] = {b.x, b.y, b.z, b.w};
      #pragma unroll
      for (int i = 0; i < 4; ++i)
        #pragma unroll
        for (int j = 0; j < 4; ++j) acc[i][j] += av[i] * bv[j];
    }
  }
  float* Cp = covp + (u64)z * MATSZ;
  #pragma unroll
  for (int i = 0; i < 4; ++i) {
    float4 v = make_float4(acc[i][0], acc[i][1], acc[i][2], acc[i][3]);
    *(float4*)&Cp[(i0 + ty * 4 + i) * NC + j0 + tx * 4] = v;
  }
}

// grid(256,4), block 256: cov = sum(slabs) - HW*mu_i*mu_j; diag -> snorm (trace fused)
__global__ void cov_reduce(const float* __restrict__ covp, const double* __restrict__ mean,
                           float* __restrict__ cov, double* __restrict__ snorm) {
  int m = blockIdx.y;
  int row = blockIdx.x, col = threadIdx.x;
  int e = row * 256 + col;
  float v = 0.0f;
  #pragma unroll
  for (int slab = 0; slab < NSLAB; ++slab)
    v += covp[(u64)(m * NSLAB + slab) * MATSZ + e];
  double mi = mean[m * NC + row], mj = mean[m * NC + col];
  float res = (float)((double)v - (double)HW * mi * mj);
  cov[m * MATSZ + e] = res;
  if (col == row) atomicAdd(&snorm[m], 1.25 * (double)res / 256.0);
}

__global__ void ns_init(const float* __restrict__ cov, const double* __restrict__ snorm,
                        float* __restrict__ Y, float* __restrict__ Z) {
  int m = blockIdx.y;
  int e = blockIdx.x * 256 + threadIdx.x;
  double inv = 1.0 / snorm[m];
  Y[m * MATSZ + e] = (float)((double)cov[m * MATSZ + e] * inv);
  Z[m * MATSZ + e] = ((e >> 8) == (e & 255)) ? 1.0f : 0.0f;
}

// ---------------- Newton-Schulz GEMMs (256x256x256, f32) ----------------
__launch_bounds__(256)
__global__ void ns_gemm_T(const float* __restrict__ Zc, const float* __restrict__ Yc,
                          float* __restrict__ T) {
  int m = blockIdx.z;
  const float* A = Zc + m * MATSZ;
  const float* B = Yc + m * MATSZ;
  int m0 = blockIdx.y * 32, n0 = blockIdx.x * 32;
  __shared__ float As[32][33], Bs[32][33];
  int tx = threadIdx.x, ty = threadIdx.y;
  int tid = ty * 16 + tx;
  float acc[2][2] = {};
  for (int k0 = 0; k0 < 256; k0 += 32) {
    __syncthreads();
    #pragma unroll
    for (int l = 0; l < 4; ++l) {
      int idx = tid + l * 256;
      int r = idx >> 5, cc = idx & 31;
      As[r][cc] = A[(m0 + r) * NC + k0 + cc];
      Bs[r][cc] = B[(k0 + r) * NC + n0 + cc];
    }
    __syncthreads();
    #pragma unroll
    for (int kk = 0; kk < 32; ++kk) {
      float a0 = As[ty][kk], a1 = As[ty + 16][kk];
      float b0 = Bs[kk][tx], b1 = Bs[kk][tx + 16];
      acc[0][0] += a0 * b0; acc[0][1] += a0 * b1;
      acc[1][0] += a1 * b0; acc[1][1] += a1 * b1;
    }
  }
  float* Cp = T + m * MATSZ;
  #pragma unroll
  for (int i = 0; i < 2; ++i)
    #pragma unroll
    for (int j = 0; j < 2; ++j) {
      int row = m0 + ty + 16 * i, col = n0 + tx + 16 * j;
      Cp[row * NC + col] = (row == col ? 1.5f : 0.0f) - 0.5f * acc[i][j];
    }
}

__launch_bounds__(256)
__global__ void ns_gemm_YZ(const float* __restrict__ Yc, const float* __restrict__ Zc,
                           const float* __restrict__ T,
                           float* __restrict__ Yn, float* __restrict__ Zn) {
  int z = blockIdx.z;
  int m = z & 3;
  bool isY = (z < 4);
  const float* A = isY ? (Yc + m * MATSZ) : (T + m * MATSZ);
  const float* B = isY ? (T + m * MATSZ) : (Zc + m * MATSZ);
  float* Cp = isY ? (Yn + m * MATSZ) : (Zn + m * MATSZ);
  int m0 = blockIdx.y * 32, n0 = blockIdx.x * 32;
  __shared__ float As[32][33], Bs[32][33];
  int tx = threadIdx.x, ty = threadIdx.y;
  int tid = ty * 16 + tx;
  float acc[2][2] = {};
  for (int k0 = 0; k0 < 256; k0 += 32) {
    __syncthreads();
    #pragma unroll
    for (int l = 0; l < 4; ++l) {
      int idx = tid + l * 256;
      int r = idx >> 5, cc = idx & 31;
      As[r][cc] = A[(m0 + r) * NC + k0 + cc];
      Bs[r][cc] = B[(k0 + r) * NC + n0 + cc];
    }
    __syncthreads();
    #pragma unroll
    for (int kk = 0; kk < 32; ++kk) {
      float a0 = As[ty][kk], a1 = As[ty + 16][kk];
      float b0 = Bs[kk][tx], b1 = Bs[kk][tx + 16];
      acc[0][0] += a0 * b0; acc[0][1] += a0 * b1;
      acc[1][0] += a1 * b0; acc[1][1] += a1 * b1;
    }
  }
  #pragma unroll
  for (int i = 0; i < 2; ++i)
    #pragma unroll
    for (int j = 0; j < 2; ++j)
      Cp[(m0 + ty + 16 * i) * NC + n0 + tx + 16 * j] = acc[i][j];
}

// ---------------- whitening apply: 64x64 tile, 4x4/thread, float4 LDS ----------------
// grid(36, 4, 4), block 256. norm = (1/sqrt(s)) * Zf * (x - mean).
__launch_bounds__(256)
__global__ void whiten_kernel(const float* __restrict__ c, const float* __restrict__ s,
                              const float* __restrict__ Zf,
                              const double* __restrict__ snorm, const double* __restrict__ mean,
                              float* __restrict__ padC_cf, float* __restrict__ padS_cf,
                              float* __restrict__ padS_cl) {
  int mat = blockIdx.z;
  const float* src = (mat < 2 ? c + mat * (NC * HW) : s + (mat - 2) * (NC * HW));
  const float* A = Zf + mat * MATSZ;
  const double* mn = mean + mat * NC;
  float wscale = (float)(1.0 / sqrt(snorm[mat]));
  int m0 = blockIdx.y * 64, n0 = blockIdx.x * 64;
  __shared__ float As[16][68], Bs[16][68];
  int tid = threadIdx.x;
  int tx = tid & 15, ty = tid >> 4;
  int li = tid >> 2, lk4 = tid & 3;       // A staging: ch row, k-quad
  int kr = tid >> 4, p4 = (tid & 15) * 4; // B staging: k row, pixel quad
  float acc[4][4] = {};
  for (int kc = 0; kc < 256; kc += 16) {
    __syncthreads();
    float4 va = *(const float4*)&A[(u64)(m0 + li) * NC + kc + lk4 * 4];
    As[lk4 * 4 + 0][li] = va.x; As[lk4 * 4 + 1][li] = va.y;
    As[lk4 * 4 + 2][li] = va.z; As[lk4 * 4 + 3][li] = va.w;
    float mk = (float)mn[kc + kr];
    float4 vb = *(const float4*)&src[(u64)(kc + kr) * HW + n0 + p4];
    vb.x -= mk; vb.y -= mk; vb.z -= mk; vb.w -= mk;
    *(float4*)&Bs[kr][p4] = vb;
    __syncthreads();
    #pragma unroll
    for (int kk = 0; kk < 16; ++kk) {
      float4 a = *(const float4*)&As[kk][ty * 4];
      float4 b = *(const float4*)&Bs[kk][tx * 4];
      float av[4] = {a.x, a.y, a.z, a.w};
      float bv[4] = {b.x, b.y, b.z, b.w};
      #pragma unroll
      for (int i = 0; i < 4; ++i)
        #pragma unroll
        for (int j = 0; j < 4; ++j) acc[i][j] += av[i] * bv[j];
    }
  }
  #pragma unroll
  for (int i = 0; i < 4; ++i) {
    int row = m0 + ty * 4 + i;
    #pragma unroll
    for (int j = 0; j < 4; ++j) {
      int n = n0 + tx * 4 + j;
      float v = acc[i][j] * wscale;
      int y = n / 48, x = n % 48;
      int ppos = (y + 1) * 50 + (x + 1);
      if (mat < 2) {
        padC_cf[(u64)mat * (NC * NPIXP) + row * NPIXP + ppos] = v;
      } else {
        padS_cf[(u64)(mat - 2) * (NC * NPIXP) + row * NPIXP + ppos] = v;
        padS_cl[(u64)(mat - 2) * (NPIX * NC) + ppos * NC + row] = v;
      }
    }
  }
}

// ---------------- transpose + bf16 split: cf [k][p] f32 -> pixel-major [p][k] bf16 hi/lo ----
__launch_bounds__(256)
__global__ void tsplit_kernel(const float* __restrict__ padC_cf, const float* __restrict__ padS_cf,
                              ushortt* __restrict__ padCk_hi, ushortt* __restrict__ padCk_lo,
                              ushortt* __restrict__ padSk_hi, ushortt* __restrict__ padSk_lo) {
  int p0 = blockIdx.x * 64;
  int by = blockIdx.y;
  const float* src = (by < 2) ? padC_cf + (u64)by * (NC * NPIXP)
                              : padS_cf + (u64)(by - 2) * (NC * NPIXP);
  ushortt* dhi = (by < 2) ? padCk_hi + (u64)by * PMSZ : padSk_hi + (u64)(by - 2) * PMSZ;
  ushortt* dlo = (by < 2) ? padCk_lo + (u64)by * PMSZ : padSk_lo + (u64)(by - 2) * PMSZ;
  __shared__ float Tk[64][68];
  int tid = threadIdx.x;
  int rr = tid >> 4, c4 = (tid & 15) * 4;
  int p = tid >> 2, kg = (tid & 3) * 16;
  for (int ks = 0; ks < 256; ks += 64) {
    __syncthreads();
    #pragma unroll
    for (int it = 0; it < 4; ++it) {
      int r = rr + it * 16;
      *(float4*)&Tk[r][c4] = *(const float4*)&src[(u64)(ks + r) * NPIXP + p0 + c4];
    }
    __syncthreads();
    __align__(16) ushortt h[16], lo[16];
    #pragma unroll
    for (int e = 0; e < 16; ++e) {
      float v = Tk[kg + e][p];
      unsigned bb = __float_as_uint(v);
      unsigned hu = (bb + 0x7FFFu + ((bb >> 16) & 1u)) >> 16;
      float hf = __uint_as_float(hu << 16);
      float rres = v - hf;
      unsigned lb = __float_as_uint(rres);
      unsigned lu = (lb + 0x7FFFu + ((lb >> 16) & 1u)) >> 16;
      h[e] = (ushortt)hu;
      lo[e] = (ushortt)lu;
    }
    u64 off = (u64)(p0 + p) * 256 + ks + kg;
    *(uint4*)&dhi[off] = *(const uint4*)&h[0];
    *(uint4*)&dhi[off + 8] = *(const uint4*)&h[8];
    *(uint4*)&dlo[off] = *(const uint4*)&lo[0];
    *(uint4*)&dlo[off + 8] = *(const uint4*)&lo[8];
  }
}

// ---------------- patch norms: rknorm = 1/||ker(ps)|| ----------------
__global__ void knorm_kernel(const float* __restrict__ padS_cl, float* __restrict__ rknorm) {
  int ps = blockIdx.x, b = blockIdx.y;
  int ys = ps / 48, xs = ps % 48;
  const float* S = padS_cl + (u64)b * (NPIX * NC);
  int ch = threadIdx.x;
  double acc = 0.0;
  #pragma unroll
  for (int dy = 0; dy < 3; ++dy)
    #pragma unroll
    for (int dx = 0; dx < 3; ++dx) {
      float v = S[((ys + dy) * 50 + xs + dx) * NC + ch];
      acc += (double)v * (double)v;
    }
  __shared__ double sd[256];
  int t = threadIdx.x;
  sd[t] = acc; __syncthreads();
  for (int st = 128; st > 0; st >>= 1) {
    if (t < st) sd[t] += sd[t + st];
    __syncthreads();
  }
  if (ch == 0) rknorm[b * HW + ps] = (float)(1.0 / sqrt(sd[0]));
}

// ---------------- MFMA Gram: G[p][q] = sum_k C[p][k]*S[q][k], split-bf16 (hh+hl+lh) --------
__launch_bounds__(256)
__global__ void gram_mfma(const ushortt* __restrict__ Ah_g, const ushortt* __restrict__ Al_g,
                          const ushortt* __restrict__ Bh_g, const ushortt* __restrict__ Bl_g,
                          float* __restrict__ G) {
  __shared__ ushortt As_hi[128 * 32], As_lo[128 * 32], Bs_hi[64 * 32], Bs_lo[64 * 32];
  int tid = threadIdx.x;
  int wv = tid >> 6, l = tid & 63, lr = l & 15, lk = l >> 4;
  int p0 = blockIdx.x * 128, q0 = blockIdx.y * 64;
  int arow = tid >> 2;
  int apart = (tid & 3) * 8;
  const ushortt* pAh0 = Ah_g + (u64)(p0 + arow) * 256 + apart;
  const ushortt* pAh1 = Ah_g + (u64)(p0 + arow + 64) * 256 + apart;
  const ushortt* pAl0 = Al_g + (u64)(p0 + arow) * 256 + apart;
  const ushortt* pAl1 = Al_g + (u64)(p0 + arow + 64) * 256 + apart;
  const ushortt* pBh  = Bh_g + (u64)(q0 + arow) * 256 + apart;
  const ushortt* pBl  = Bl_g + (u64)(q0 + arow) * 256 + apart;
  float4 rAh0 = *(const float4*)pAh0;
  float4 rAh1 = *(const float4*)pAh1;
  float4 rAl0 = *(const float4*)pAl0;
  float4 rAl1 = *(const float4*)pAl1;
  float4 rBh  = *(const float4*)pBh;
  float4 rBl  = *(const float4*)pBl;
  f32x4 acc[2][4];
  #pragma unroll
  for (int a = 0; a < 2; ++a)
    #pragma unroll
    for (int b = 0; b < 4; ++b)
      #pragma unroll
      for (int e = 0; e < 4; ++e) acc[a][b][e] = 0.0f;
  for (int k0 = 0; k0 < 256; k0 += 32) {
    __syncthreads();
    *(float4*)&As_hi[arow * 32 + apart] = rAh0;
    *(float4*)&As_hi[(arow + 64) * 32 + apart] = rAh1;
    *(float4*)&As_lo[arow * 32 + apart] = rAl0;
    *(float4*)&As_lo[(arow + 64) * 32 + apart] = rAl1;
    *(float4*)&Bs_hi[arow * 32 + apart] = rBh;
    *(float4*)&Bs_lo[arow * 32 + apart] = rBl;
    __syncthreads();
    if (k0 + 32 < 256) {
      rAh0 = *(const float4*)(pAh0 + k0 + 32);
      rAh1 = *(const float4*)(pAh1 + k0 + 32);
      rAl0 = *(const float4*)(pAl0 + k0 + 32);
      rAl1 = *(const float4*)(pAl1 + k0 + 32);
      rBh  = *(const float4*)(pBh + k0 + 32);
      rBl  = *(const float4*)(pBl + k0 + 32);
    }
    bhalf8 Ah[2], Al[2], Bh[4], Bl[4];
    #pragma unroll
    for (int a = 0; a < 2; ++a) {
      int off = (wv * 32 + a * 16 + lr) * 32 + lk * 8;
      Ah[a] = *(const bhalf8*)&As_hi[off];
      Al[a] = *(const bhalf8*)&As_lo[off];
    }
    #pragma unroll
    for (int b = 0; b < 4; ++b) {
      int off = (b * 16 + lr) * 32 + lk * 8;
      Bh[b] = *(const bhalf8*)&Bs_hi[off];
      Bl[b] = *(const bhalf8*)&Bs_lo[off];
    }
    #pragma unroll
    for (int a = 0; a < 2; ++a)
      #pragma unroll
      for (int b = 0; b < 4; ++b) {
        acc[a][b] = __builtin_amdgcn_mfma_f32_16x16x32_bf16(Ah[a], Bh[b], acc[a][b], 0, 0, 0);
        acc[a][b] = __builtin_amdgcn_mfma_f32_16x16x32_bf16(Ah[a], Bl[b], acc[a][b], 0, 0, 0);
        acc[a][b] = __builtin_amdgcn_mfma_f32_16x16x32_bf16(Al[a], Bh[b], acc[a][b], 0, 0, 0);
      }
  }
  #pragma unroll
  for (int a = 0; a < 2; ++a)
    #pragma unroll
    for (int b = 0; b < 4; ++b)
      #pragma unroll
      for (int r = 0; r < 4; ++r) {
        int p = p0 + wv * 32 + a * 16 + lk * 4 + r;
        int q = q0 + b * 16 + lr;
        G[(u64)p * NPIXP + q] = acc[a][b][r];
      }
}

// ---------------- fused stencil + argmax ----------------
__launch_bounds__(256)
__global__ void scoremax_kernel(const float* __restrict__ G, const float* __restrict__ rknorm,
                                u64* __restrict__ rmax, int b) {
  int y = blockIdx.x, ys = blockIdx.y;
  __shared__ float Gt[3][50][50];
  __shared__ float sc[48][48];
  __shared__ float rkl[48];
  int tid = threadIdx.x;
  for (int t = tid; t < 7500; t += 256) {
    int dy = t / 2500, rem = t % 2500;
    int u = rem / 50, v = rem - u * 50;
    Gt[dy][u][v] = G[(u64)((y + dy) * 50 + u) * NPIXP + (ys + dy) * 50 + v];
  }
  if (tid < 48) rkl[tid] = rknorm[b * HW + ys * 48 + tid];
  __syncthreads();
  #pragma unroll
  for (int k = 0; k < 9; ++k) {
    int idx = tid + k * 256;
    int x = idx / 48, xs = idx - x * 48;
    float v = 0.0f;
    #pragma unroll
    for (int dy = 0; dy < 3; ++dy)
      #pragma unroll
      for (int dx = 0; dx < 3; ++dx)
        v += Gt[dy][x + dx][xs + dx];
    sc[x][xs] = v * rkl[xs];
  }
  __syncthreads();
  if (tid < 48) {
    float best = -1e30f; int bxs = 0;
    for (int xs = 0; xs < 48; ++xs) {
      float v = sc[tid][xs];
      if (v > best) { best = v; bxs = xs; }   // strict >: smallest xs on ties
    }
    int ps = ys * 48 + bxs;
    unsigned ub = __float_as_uint(best);
    unsigned enc = (ub & 0x80000000u) ? ~ub : (ub | 0x80000000u);
    u64 key = ((u64)enc << 32) | (u64)(2303 - ps);
    atomicMax(&rmax[(u64)b * HW + y * 48 + tid], key);
  }
}

// ---------------- reassemble: paste chosen patches + overlap normalize ----------------
__global__ void reassemble_kernel(const float* __restrict__ padS_cl, const u64* __restrict__ rmax,
                                  float* __restrict__ rF_cl) {
  int pix = blockIdx.x, b = blockIdx.y;
  int y = pix / 48, x = pix % 48;
  const u64* rm = rmax + (u64)b * HW;
  const float* S = padS_cl + (u64)b * (NPIX * NC);
  int ch = threadIdx.x;
  float sum = 0.0f;
  #pragma unroll
  for (int i = 0; i < 3; ++i)
    #pragma unroll
    for (int j = 0; j < 3; ++j) {
      int yn = y + 1 - i, xn = x + 1 - j;
      if (yn >= 0 && yn < 48 && xn >= 0 && xn < 48) {
        int ps = 2303 - (int)(unsigned)(rm[yn * 48 + xn] & 0xFFFFFFFFu);
        int ys = ps / 48, xs = ps % 48;
        sum += S[((ys + i) * 50 + xs + j) * NC + ch];
      }
    }
  float cy = (y == 0 || y == 47) ? 2.0f : 3.0f;
  float cx = (x == 0 || x == 47) ? 2.0f : 3.0f;
  rF_cl[(u64)b * (HW * NC) + pix * NC + ch] = sum / (cy * cx);
}

// ---------------- coloring: 64x64 tile, 4x4/thread, float4 LDS ----------------
// grid(36, 4, 2), block 256. out = sqrt(s)*Yf*rF + mean_s.
__launch_bounds__(256)
__global__ void coloring_kernel(const float* __restrict__ Yf, const double* __restrict__ snorm,
                                const double* __restrict__ mean, const float* __restrict__ rF_cl,
                                float* __restrict__ out) {
  int b = blockIdx.z;
  const float* A = Yf + (2 + b) * MATSZ;
  const float* Bp = rF_cl + (u64)b * (HW * NC);
  const double* mn = mean + (2 + b) * NC;
  float cscale = (float)sqrt(snorm[2 + b]);
  int m0 = blockIdx.y * 64, n0 = blockIdx.x * 64;
  __shared__ float As[16][68], Bs[16][68];
  int tid = threadIdx.x;
  int tx = tid & 15, ty = tid >> 4;
  int li = tid >> 2, lk4 = tid & 3;       // A staging
  int pix = tid >> 2, kq = (tid & 3) * 4; // B staging: pixel row, k-quad
  float acc[4][4] = {};
  for (int kc = 0; kc < 256; kc += 16) {
    __syncthreads();
    float4 va = *(const float4*)&A[(u64)(m0 + li) * NC + kc + lk4 * 4];
    As[lk4 * 4 + 0][li] = va.x; As[lk4 * 4 + 1][li] = va.y;
    As[lk4 * 4 + 2][li] = va.z; As[lk4 * 4 + 3][li] = va.w;
    float4 vb = *(const float4*)&Bp[(u64)(n0 + pix) * NC + kc + kq];
    Bs[kq + 0][pix] = vb.x; Bs[kq + 1][pix] = vb.y;
    Bs[kq + 2][pix] = vb.z; Bs[kq + 3][pix] = vb.w;
    __syncthreads();
    #pragma unroll
    for (int kk = 0; kk < 16; ++kk) {
      float4 a = *(const float4*)&As[kk][ty * 4];
      float4 b2 = *(const float4*)&Bs[kk][tx * 4];
      float av[4] = {a.x, a.y, a.z, a.w};
      float bv[4] = {b2.x, b2.y, b2.z, b2.w};
      #pragma unroll
      for (int i = 0; i < 4; ++i)
        #pragma unroll
        for (int j = 0; j < 4; ++j) acc[i][j] += av[i] * bv[j];
    }
  }
  #pragma unroll
  for (int i = 0; i < 4; ++i) {
    int row = m0 + ty * 4 + i;
    float madd = (float)mn[row];
    float4 v = make_float4(acc[i][0] * cscale + madd, acc[i][1] * cscale + madd,
                           acc[i][2] * cscale + madd, acc[i][3] * cscale + madd);
    *(float4*)&out[(u64)b * (NC * HW) + (u64)row * HW + n0 + tx * 4] = v;
  }
}

// ---------------- host ----------------
extern "C" void kernel_launch(void* const* d_in, const int* in_sizes, int n_in,
                              void* d_out, int out_size, void* d_ws, size_t ws_size,
                              hipStream_t stream) {
  const float* c = (const float*)d_in[0];
  const float* s = (const float*)d_in[1];
  float* out = (float*)d_out;

  char* ws = (char*)d_ws;
  size_t off = 0;
  auto alloc = [&](size_t bytes) {
    void* p = ws + off;
    off = (off + bytes + 255) & ~(size_t)255;
    return p;
  };
  double* mean   = (double*)alloc(4 * NC * sizeof(double));
  float* cov     = (float*)alloc((size_t)4 * MATSZ * sizeof(float));
  float* covp    = (float*)alloc((size_t)4 * NSLAB * MATSZ * sizeof(float));
  float* Ya      = (float*)alloc((size_t)4 * MATSZ * sizeof(float));
  float* Yb      = (float*)alloc((size_t)4 * MATSZ * sizeof(float));
  float* Za      = (float*)alloc((size_t)4 * MATSZ * sizeof(float));
  float* Zb      = (float*)alloc((size_t)4 * MATSZ * sizeof(float));
  float* T       = (float*)alloc((size_t)4 * MATSZ * sizeof(float));
  float* padC_cf = (float*)alloc((size_t)2 * NC * NPIXP * sizeof(float));
  float* padS_cf = (float*)alloc((size_t)2 * NC * NPIXP * sizeof(float));
  float* padS_cl = (float*)alloc((size_t)2 * NPIX * NC * sizeof(float));
  ushortt* padCk_hi = (ushortt*)alloc((size_t)2 * PMSZ * sizeof(ushortt));
  ushortt* padCk_lo = (ushortt*)alloc((size_t)2 * PMSZ * sizeof(ushortt));
  ushortt* padSk_hi = (ushortt*)alloc((size_t)2 * PMSZ * sizeof(ushortt));
  ushortt* padSk_lo = (ushortt*)alloc((size_t)2 * PMSZ * sizeof(ushortt));
  float* rknorm  = (float*)alloc((size_t)2 * HW * sizeof(float));
  float* rF_cl   = (float*)alloc((size_t)2 * HW * NC * sizeof(float));
  float* G       = (float*)alloc((size_t)NPIXP * NPIXP * sizeof(float));
  u64*   rmax    = (u64*)alloc((size_t)2 * HW * sizeof(u64));
  double* snorm  = (double*)alloc(4 * sizeof(double));

  size_t padBytes = (size_t)(2 * NC * NPIXP + 2 * NC * NPIXP + 2 * NPIX * NC) * sizeof(float);
  hipMemsetAsync(padC_cf, 0, padBytes, stream);
  hipMemsetAsync(rmax, 0, (size_t)2 * HW * sizeof(u64) + 4 * sizeof(double), stream);

  mean_kernel<<<dim3(256, 4), 64, 0, stream>>>(c, s, mean);
  cov_part<<<dim3(4, 4, 4 * NSLAB), dim3(16, 16), 0, stream>>>(c, s, covp);
  cov_reduce<<<dim3(256, 4), 256, 0, stream>>>(covp, mean, cov, snorm);
  ns_init<<<dim3(256, 4), 256, 0, stream>>>(cov, snorm, Ya, Za);

  float *Yc = Ya, *Zc = Za, *Yn = Yb, *Zn = Zb;
  for (int it = 0; it < NS_ITERS; ++it) {
    ns_gemm_T<<<dim3(8, 8, 4), dim3(16, 16), 0, stream>>>(Zc, Yc, T);
    ns_gemm_YZ<<<dim3(8, 8, 8), dim3(16, 16), 0, stream>>>(Yc, Zc, T, Yn, Zn);
    float* t1 = Yc; Yc = Yn; Yn = t1;
    float* t2 = Zc; Zc = Zn; Zn = t2;
  }

  whiten_kernel<<<dim3(36, 4, 4), 256, 0, stream>>>(c, s, Zc, snorm, mean,
                                                    padC_cf, padS_cf, padS_cl);
  tsplit_kernel<<<dim3(40, 4), 256, 0, stream>>>(padC_cf, padS_cf,
                                                 padCk_hi, padCk_lo, padSk_hi, padSk_lo);
  knorm_kernel<<<dim3(2304, 2), 256, 0, stream>>>(padS_cl, rknorm);

  for (int b = 0; b < 2; ++b) {
    gram_mfma<<<dim3(20, 40), 256, 0, stream>>>(padCk_hi + (u64)b * PMSZ,
                                                padCk_lo + (u64)b * PMSZ,
                                                padSk_hi + (u64)b * PMSZ,
                                                padSk_lo + (u64)b * PMSZ, G);
    scoremax_kernel<<<dim3(48, 48), 256, 0, stream>>>(G, rknorm, rmax, b);
  }

  reassemble_kernel<<<dim3(2304, 2), 256, 0, stream>>>(padS_cl, rmax, rF_cl);
  coloring_kernel<<<dim3(36, 4, 2), 256, 0, stream>>>(Yc, snorm, mean, rF_cl, out);
}

// Round 12
// 322.142 us; speedup vs baseline: 3.1102x; 1.1167x over previous
//
#include <hip/hip_runtime.h>
#include <math.h>

#define HW 2304       // 48*48
#define NC 256        // channels
#define NPIX 2500     // 50*50 padded grid
#define NPIXP 2560    // padded row stride for channel-first buffers / Gram
#define MATSZ 65536   // 256*256
#define NS_ITERS 5    // iter0 folded + 4 GEMM iterations
#define NSLAB 6
#define KSLAB 384     // 2304/6
#define PMSZ (2560 * 256)  // pixel-major buffer elems per batch
#define GSZ ((u64)NPIXP * NPIXP)

typedef unsigned long long u64;
typedef unsigned short ushortt;
typedef __attribute__((ext_vector_type(8))) short bhalf8;
typedef __attribute__((ext_vector_type(4))) float f32x4;

// ---------------- means + trace (f64): snorm[m] = 1.25*trace/256 ----------------
__global__ void mean_kernel(const float* __restrict__ c, const float* __restrict__ s,
                            double* __restrict__ mean, double* __restrict__ snorm) {
  int ch = blockIdx.x, m = blockIdx.y;
  const float* src = (m < 2 ? c + m * (NC * HW) : s + (m - 2) * (NC * HW)) + ch * HW;
  double acc = 0.0, acc2 = 0.0;
  for (int n = threadIdx.x; n < HW; n += 64) {
    double v = (double)src[n];
    acc += v; acc2 += v * v;
  }
  for (int o = 32; o > 0; o >>= 1) {
    acc += __shfl_down(acc, o);
    acc2 += __shfl_down(acc2, o);
  }
  if (threadIdx.x == 0) {
    mean[m * NC + ch] = acc / (double)HW;
    double diag = acc2 - acc * acc / (double)HW;   // = sum x^2 - HW*mu^2
    atomicAdd(&snorm[m], 1.25 * diag / 256.0);
  }
}

// ---------------- covariance partials: raw sum(x*y), 64x64 tile, 4x4/thread ----------------
__launch_bounds__(256)
__global__ void cov_part(const float* __restrict__ c, const float* __restrict__ s,
                         float* __restrict__ covp) {
  int z = blockIdx.z;
  int m = z / NSLAB, slab = z % NSLAB;
  const float* src = (m < 2 ? c + m * (NC * HW) : s + (m - 2) * (NC * HW));
  int i0 = blockIdx.y * 64, j0 = blockIdx.x * 64;
  int kb = slab * KSLAB;
  __shared__ float As[16][64], Bs[16][64];
  int tx = threadIdx.x, ty = threadIdx.y;
  int tid = ty * 16 + tx;
  int li = tid >> 2;
  int lk4 = tid & 3;
  float acc[4][4] = {};
  for (int kc = 0; kc < KSLAB; kc += 16) {
    __syncthreads();
    float4 va = *(const float4*)&src[(u64)(i0 + li) * HW + kb + kc + lk4 * 4];
    float4 vb = *(const float4*)&src[(u64)(j0 + li) * HW + kb + kc + lk4 * 4];
    As[lk4 * 4 + 0][li] = va.x; As[lk4 * 4 + 1][li] = va.y;
    As[lk4 * 4 + 2][li] = va.z; As[lk4 * 4 + 3][li] = va.w;
    Bs[lk4 * 4 + 0][li] = vb.x; Bs[lk4 * 4 + 1][li] = vb.y;
    Bs[lk4 * 4 + 2][li] = vb.z; Bs[lk4 * 4 + 3][li] = vb.w;
    __syncthreads();
    #pragma unroll
    for (int kk = 0; kk < 16; ++kk) {
      float4 a = *(const float4*)&As[kk][ty * 4];
      float4 b = *(const float4*)&Bs[kk][tx * 4];
      float av[4] = {a.x, a.y, a.z, a.w};
      float bv[4] = {b.x, b.y, b.z, b.w};
      #pragma unroll
      for (int i = 0; i < 4; ++i)
        #pragma unroll
        for (int j = 0; j < 4; ++j) acc[i][j] += av[i] * bv[j];
    }
  }
  float* Cp = covp + (u64)z * MATSZ;
  #pragma unroll
  for (int i = 0; i < 4; ++i) {
    float4 v = make_float4(acc[i][0], acc[i][1], acc[i][2], acc[i][3]);
    *(float4*)&Cp[(i0 + ty * 4 + i) * NC + j0 + tx * 4] = v;
  }
}

// grid(256,4), block 256. Y0 = (cov)/s; Z1 = T0 = 1.5I - 0.5*Y0 (NS iter0 folded).
__global__ void cov_reduce(const float* __restrict__ covp, const double* __restrict__ mean,
                           const double* __restrict__ snorm,
                           float* __restrict__ Y0, float* __restrict__ Z1) {
  int m = blockIdx.y;
  int row = blockIdx.x, col = threadIdx.x;
  int e = row * 256 + col;
  float v = 0.0f;
  #pragma unroll
  for (int slab = 0; slab < NSLAB; ++slab)
    v += covp[(u64)(m * NSLAB + slab) * MATSZ + e];
  double mi = mean[m * NC + row], mj = mean[m * NC + col];
  float res = (float)((double)v - (double)HW * mi * mj);
  float inv = (float)(1.0 / snorm[m]);
  float y0 = res * inv;
  Y0[m * MATSZ + e] = y0;
  Z1[m * MATSZ + e] = ((row == col) ? 1.5f : 0.0f) - 0.5f * y0;
}

// ---------------- Newton-Schulz GEMMs (256x256x256, f32) ----------------
// iter0 Y-update: Y1 = Y0 * T0.  grid(8,8,4)
__launch_bounds__(256)
__global__ void ns_gemm_Y(const float* __restrict__ Y0, const float* __restrict__ T0,
                          float* __restrict__ Y1) {
  int m = blockIdx.z;
  const float* A = Y0 + m * MATSZ;
  const float* B = T0 + m * MATSZ;
  float* Cp = Y1 + m * MATSZ;
  int m0 = blockIdx.y * 32, n0 = blockIdx.x * 32;
  __shared__ float As[32][33], Bs[32][33];
  int tx = threadIdx.x, ty = threadIdx.y;
  int tid = ty * 16 + tx;
  float acc[2][2] = {};
  for (int k0 = 0; k0 < 256; k0 += 32) {
    __syncthreads();
    #pragma unroll
    for (int l = 0; l < 4; ++l) {
      int idx = tid + l * 256;
      int r = idx >> 5, cc = idx & 31;
      As[r][cc] = A[(m0 + r) * NC + k0 + cc];
      Bs[r][cc] = B[(k0 + r) * NC + n0 + cc];
    }
    __syncthreads();
    #pragma unroll
    for (int kk = 0; kk < 32; ++kk) {
      float a0 = As[ty][kk], a1 = As[ty + 16][kk];
      float b0 = Bs[kk][tx], b1 = Bs[kk][tx + 16];
      acc[0][0] += a0 * b0; acc[0][1] += a0 * b1;
      acc[1][0] += a1 * b0; acc[1][1] += a1 * b1;
    }
  }
  #pragma unroll
  for (int i = 0; i < 2; ++i)
    #pragma unroll
    for (int j = 0; j < 2; ++j)
      Cp[(m0 + ty + 16 * i) * NC + n0 + tx + 16 * j] = acc[i][j];
}

__launch_bounds__(256)
__global__ void ns_gemm_T(const float* __restrict__ Zc, const float* __restrict__ Yc,
                          float* __restrict__ T) {
  int m = blockIdx.z;
  const float* A = Zc + m * MATSZ;
  const float* B = Yc + m * MATSZ;
  int m0 = blockIdx.y * 32, n0 = blockIdx.x * 32;
  __shared__ float As[32][33], Bs[32][33];
  int tx = threadIdx.x, ty = threadIdx.y;
  int tid = ty * 16 + tx;
  float acc[2][2] = {};
  for (int k0 = 0; k0 < 256; k0 += 32) {
    __syncthreads();
    #pragma unroll
    for (int l = 0; l < 4; ++l) {
      int idx = tid + l * 256;
      int r = idx >> 5, cc = idx & 31;
      As[r][cc] = A[(m0 + r) * NC + k0 + cc];
      Bs[r][cc] = B[(k0 + r) * NC + n0 + cc];
    }
    __syncthreads();
    #pragma unroll
    for (int kk = 0; kk < 32; ++kk) {
      float a0 = As[ty][kk], a1 = As[ty + 16][kk];
      float b0 = Bs[kk][tx], b1 = Bs[kk][tx + 16];
      acc[0][0] += a0 * b0; acc[0][1] += a0 * b1;
      acc[1][0] += a1 * b0; acc[1][1] += a1 * b1;
    }
  }
  float* Cp = T + m * MATSZ;
  #pragma unroll
  for (int i = 0; i < 2; ++i)
    #pragma unroll
    for (int j = 0; j < 2; ++j) {
      int row = m0 + ty + 16 * i, col = n0 + tx + 16 * j;
      Cp[row * NC + col] = (row == col ? 1.5f : 0.0f) - 0.5f * acc[i][j];
    }
}

__launch_bounds__(256)
__global__ void ns_gemm_YZ(const float* __restrict__ Yc, const float* __restrict__ Zc,
                           const float* __restrict__ T,
                           float* __restrict__ Yn, float* __restrict__ Zn) {
  int z = blockIdx.z;
  int m = z & 3;
  bool isY = (z < 4);
  const float* A = isY ? (Yc + m * MATSZ) : (T + m * MATSZ);
  const float* B = isY ? (T + m * MATSZ) : (Zc + m * MATSZ);
  float* Cp = isY ? (Yn + m * MATSZ) : (Zn + m * MATSZ);
  int m0 = blockIdx.y * 32, n0 = blockIdx.x * 32;
  __shared__ float As[32][33], Bs[32][33];
  int tx = threadIdx.x, ty = threadIdx.y;
  int tid = ty * 16 + tx;
  float acc[2][2] = {};
  for (int k0 = 0; k0 < 256; k0 += 32) {
    __syncthreads();
    #pragma unroll
    for (int l = 0; l < 4; ++l) {
      int idx = tid + l * 256;
      int r = idx >> 5, cc = idx & 31;
      As[r][cc] = A[(m0 + r) * NC + k0 + cc];
      Bs[r][cc] = B[(k0 + r) * NC + n0 + cc];
    }
    __syncthreads();
    #pragma unroll
    for (int kk = 0; kk < 32; ++kk) {
      float a0 = As[ty][kk], a1 = As[ty + 16][kk];
      float b0 = Bs[kk][tx], b1 = Bs[kk][tx + 16];
      acc[0][0] += a0 * b0; acc[0][1] += a0 * b1;
      acc[1][0] += a1 * b0; acc[1][1] += a1 * b1;
    }
  }
  #pragma unroll
  for (int i = 0; i < 2; ++i)
    #pragma unroll
    for (int j = 0; j < 2; ++j)
      Cp[(m0 + ty + 16 * i) * NC + n0 + tx + 16 * j] = acc[i][j];
}

// ---------------- whitening apply: 64x64 tile, 4x4/thread, float4 LDS ----------------
__launch_bounds__(256)
__global__ void whiten_kernel(const float* __restrict__ c, const float* __restrict__ s,
                              const float* __restrict__ Zf,
                              const double* __restrict__ snorm, const double* __restrict__ mean,
                              float* __restrict__ padC_cf, float* __restrict__ padS_cf,
                              float* __restrict__ padS_cl) {
  int mat = blockIdx.z;
  const float* src = (mat < 2 ? c + mat * (NC * HW) : s + (mat - 2) * (NC * HW));
  const float* A = Zf + mat * MATSZ;
  const double* mn = mean + mat * NC;
  float wscale = (float)(1.0 / sqrt(snorm[mat]));
  int m0 = blockIdx.y * 64, n0 = blockIdx.x * 64;
  __shared__ float As[16][68], Bs[16][68];
  int tid = threadIdx.x;
  int tx = tid & 15, ty = tid >> 4;
  int li = tid >> 2, lk4 = tid & 3;
  int kr = tid >> 4, p4 = (tid & 15) * 4;
  float acc[4][4] = {};
  for (int kc = 0; kc < 256; kc += 16) {
    __syncthreads();
    float4 va = *(const float4*)&A[(u64)(m0 + li) * NC + kc + lk4 * 4];
    As[lk4 * 4 + 0][li] = va.x; As[lk4 * 4 + 1][li] = va.y;
    As[lk4 * 4 + 2][li] = va.z; As[lk4 * 4 + 3][li] = va.w;
    float mk = (float)mn[kc + kr];
    float4 vb = *(const float4*)&src[(u64)(kc + kr) * HW + n0 + p4];
    vb.x -= mk; vb.y -= mk; vb.z -= mk; vb.w -= mk;
    *(float4*)&Bs[kr][p4] = vb;
    __syncthreads();
    #pragma unroll
    for (int kk = 0; kk < 16; ++kk) {
      float4 a = *(const float4*)&As[kk][ty * 4];
      float4 b = *(const float4*)&Bs[kk][tx * 4];
      float av[4] = {a.x, a.y, a.z, a.w};
      float bv[4] = {b.x, b.y, b.z, b.w};
      #pragma unroll
      for (int i = 0; i < 4; ++i)
        #pragma unroll
        for (int j = 0; j < 4; ++j) acc[i][j] += av[i] * bv[j];
    }
  }
  #pragma unroll
  for (int i = 0; i < 4; ++i) {
    int row = m0 + ty * 4 + i;
    #pragma unroll
    for (int j = 0; j < 4; ++j) {
      int n = n0 + tx * 4 + j;
      float v = acc[i][j] * wscale;
      int y = n / 48, x = n % 48;
      int ppos = (y + 1) * 50 + (x + 1);
      if (mat < 2) {
        padC_cf[(u64)mat * (NC * NPIXP) + row * NPIXP + ppos] = v;
      } else {
        padS_cf[(u64)(mat - 2) * (NC * NPIXP) + row * NPIXP + ppos] = v;
        padS_cl[(u64)(mat - 2) * (NPIX * NC) + ppos * NC + row] = v;
      }
    }
  }
}

// ---------------- transpose + bf16 split + per-pixel sumsq (style) ----------------
__launch_bounds__(256)
__global__ void tsplit_kernel(const float* __restrict__ padC_cf, const float* __restrict__ padS_cf,
                              ushortt* __restrict__ padCk_hi, ushortt* __restrict__ padCk_lo,
                              ushortt* __restrict__ padSk_hi, ushortt* __restrict__ padSk_lo,
                              float* __restrict__ ssq) {
  int p0 = blockIdx.x * 64;
  int by = blockIdx.y;
  const float* src = (by < 2) ? padC_cf + (u64)by * (NC * NPIXP)
                              : padS_cf + (u64)(by - 2) * (NC * NPIXP);
  ushortt* dhi = (by < 2) ? padCk_hi + (u64)by * PMSZ : padSk_hi + (u64)(by - 2) * PMSZ;
  ushortt* dlo = (by < 2) ? padCk_lo + (u64)by * PMSZ : padSk_lo + (u64)(by - 2) * PMSZ;
  __shared__ float Tk[64][68];
  int tid = threadIdx.x;
  int rr = tid >> 4, c4 = (tid & 15) * 4;
  int p = tid >> 2, kg = (tid & 3) * 16;
  float sq = 0.0f;
  for (int ks = 0; ks < 256; ks += 64) {
    __syncthreads();
    #pragma unroll
    for (int it = 0; it < 4; ++it) {
      int r = rr + it * 16;
      *(float4*)&Tk[r][c4] = *(const float4*)&src[(u64)(ks + r) * NPIXP + p0 + c4];
    }
    __syncthreads();
    __align__(16) ushortt h[16], lo[16];
    #pragma unroll
    for (int e = 0; e < 16; ++e) {
      float v = Tk[kg + e][p];
      sq += v * v;
      unsigned bb = __float_as_uint(v);
      unsigned hu = (bb + 0x7FFFu + ((bb >> 16) & 1u)) >> 16;
      float hf = __uint_as_float(hu << 16);
      float rres = v - hf;
      unsigned lb = __float_as_uint(rres);
      unsigned lu = (lb + 0x7FFFu + ((lb >> 16) & 1u)) >> 16;
      h[e] = (ushortt)hu;
      lo[e] = (ushortt)lu;
    }
    u64 off = (u64)(p0 + p) * 256 + ks + kg;
    *(uint4*)&dhi[off] = *(const uint4*)&h[0];
    *(uint4*)&dhi[off + 8] = *(const uint4*)&h[8];
    *(uint4*)&dlo[off] = *(const uint4*)&lo[0];
    *(uint4*)&dlo[off + 8] = *(const uint4*)&lo[8];
  }
  // reduce the 4 threads covering pixel p (consecutive lanes)
  sq += __shfl_down(sq, 2);
  sq += __shfl_down(sq, 1);
  if (by >= 2 && (tid & 3) == 0 && (p0 + p) < NPIX)
    ssq[(u64)(by - 2) * NPIX + p0 + p] = sq;
}

// ---------------- MFMA Gram: G[p][q] = sum_k C[p][k]*S[q][k], split-bf16, z=batch -------
__launch_bounds__(256)
__global__ void gram_mfma(const ushortt* __restrict__ Ah_b, const ushortt* __restrict__ Al_b,
                          const ushortt* __restrict__ Bh_b, const ushortt* __restrict__ Bl_b,
                          float* __restrict__ Gb) {
  int bz = blockIdx.z;
  const ushortt* Ah_g = Ah_b + (u64)bz * PMSZ;
  const ushortt* Al_g = Al_b + (u64)bz * PMSZ;
  const ushortt* Bh_g = Bh_b + (u64)bz * PMSZ;
  const ushortt* Bl_g = Bl_b + (u64)bz * PMSZ;
  float* G = Gb + (u64)bz * GSZ;
  __shared__ ushortt As_hi[128 * 32], As_lo[128 * 32], Bs_hi[64 * 32], Bs_lo[64 * 32];
  int tid = threadIdx.x;
  int wv = tid >> 6, l = tid & 63, lr = l & 15, lk = l >> 4;
  int p0 = blockIdx.x * 128, q0 = blockIdx.y * 64;
  int arow = tid >> 2;
  int apart = (tid & 3) * 8;
  const ushortt* pAh0 = Ah_g + (u64)(p0 + arow) * 256 + apart;
  const ushortt* pAh1 = Ah_g + (u64)(p0 + arow + 64) * 256 + apart;
  const ushortt* pAl0 = Al_g + (u64)(p0 + arow) * 256 + apart;
  const ushortt* pAl1 = Al_g + (u64)(p0 + arow + 64) * 256 + apart;
  const ushortt* pBh  = Bh_g + (u64)(q0 + arow) * 256 + apart;
  const ushortt* pBl  = Bl_g + (u64)(q0 + arow) * 256 + apart;
  float4 rAh0 = *(const float4*)pAh0;
  float4 rAh1 = *(const float4*)pAh1;
  float4 rAl0 = *(const float4*)pAl0;
  float4 rAl1 = *(const float4*)pAl1;
  float4 rBh  = *(const float4*)pBh;
  float4 rBl  = *(const float4*)pBl;
  f32x4 acc[2][4];
  #pragma unroll
  for (int a = 0; a < 2; ++a)
    #pragma unroll
    for (int b = 0; b < 4; ++b)
      #pragma unroll
      for (int e = 0; e < 4; ++e) acc[a][b][e] = 0.0f;
  for (int k0 = 0; k0 < 256; k0 += 32) {
    __syncthreads();
    *(float4*)&As_hi[arow * 32 + apart] = rAh0;
    *(float4*)&As_hi[(arow + 64) * 32 + apart] = rAh1;
    *(float4*)&As_lo[arow * 32 + apart] = rAl0;
    *(float4*)&As_lo[(arow + 64) * 32 + apart] = rAl1;
    *(float4*)&Bs_hi[arow * 32 + apart] = rBh;
    *(float4*)&Bs_lo[arow * 32 + apart] = rBl;
    __syncthreads();
    if (k0 + 32 < 256) {
      rAh0 = *(const float4*)(pAh0 + k0 + 32);
      rAh1 = *(const float4*)(pAh1 + k0 + 32);
      rAl0 = *(const float4*)(pAl0 + k0 + 32);
      rAl1 = *(const float4*)(pAl1 + k0 + 32);
      rBh  = *(const float4*)(pBh + k0 + 32);
      rBl  = *(const float4*)(pBl + k0 + 32);
    }
    bhalf8 Ah[2], Al[2], Bh[4], Bl[4];
    #pragma unroll
    for (int a = 0; a < 2; ++a) {
      int off = (wv * 32 + a * 16 + lr) * 32 + lk * 8;
      Ah[a] = *(const bhalf8*)&As_hi[off];
      Al[a] = *(const bhalf8*)&As_lo[off];
    }
    #pragma unroll
    for (int b = 0; b < 4; ++b) {
      int off = (b * 16 + lr) * 32 + lk * 8;
      Bh[b] = *(const bhalf8*)&Bs_hi[off];
      Bl[b] = *(const bhalf8*)&Bs_lo[off];
    }
    #pragma unroll
    for (int a = 0; a < 2; ++a)
      #pragma unroll
      for (int b = 0; b < 4; ++b) {
        acc[a][b] = __builtin_amdgcn_mfma_f32_16x16x32_bf16(Ah[a], Bh[b], acc[a][b], 0, 0, 0);
        acc[a][b] = __builtin_amdgcn_mfma_f32_16x16x32_bf16(Ah[a], Bl[b], acc[a][b], 0, 0, 0);
        acc[a][b] = __builtin_amdgcn_mfma_f32_16x16x32_bf16(Al[a], Bh[b], acc[a][b], 0, 0, 0);
      }
  }
  #pragma unroll
  for (int a = 0; a < 2; ++a)
    #pragma unroll
    for (int b = 0; b < 4; ++b)
      #pragma unroll
      for (int r = 0; r < 4; ++r) {
        int p = p0 + wv * 32 + a * 16 + lk * 4 + r;
        int q = q0 + b * 16 + lr;
        G[(u64)p * NPIXP + q] = acc[a][b][r];
      }
}

// ---------------- fused stencil + rknorm + argmax, z=batch ----------------
__launch_bounds__(256)
__global__ void scoremax_kernel(const float* __restrict__ Gb, const float* __restrict__ ssq,
                                u64* __restrict__ rmax) {
  int y = blockIdx.x, ys = blockIdx.y, b = blockIdx.z;
  const float* G = Gb + (u64)b * GSZ;
  const float* sq = ssq + (u64)b * NPIX;
  __shared__ float Gt[3][50][50];
  __shared__ float sc[48][48];
  __shared__ float sr[152];
  __shared__ float rkl[48];
  int tid = threadIdx.x;
  for (int t = tid; t < 7500; t += 256) {
    int dy = t / 2500, rem = t % 2500;
    int u = rem / 50, v = rem - u * 50;
    Gt[dy][u][v] = G[(u64)((y + dy) * 50 + u) * NPIXP + (ys + dy) * 50 + v];
  }
  if (tid < 150) {
    int dy = tid / 50, v = tid - dy * 50;
    sr[dy * 50 + v] = sq[(ys + dy) * 50 + v];
  }
  __syncthreads();
  if (tid < 48) {
    float t = 0.0f;
    #pragma unroll
    for (int dy = 0; dy < 3; ++dy)
      #pragma unroll
      for (int dx = 0; dx < 3; ++dx) t += sr[dy * 50 + tid + dx];
    rkl[tid] = 1.0f / sqrtf(t);
  }
  __syncthreads();
  #pragma unroll
  for (int k = 0; k < 9; ++k) {
    int idx = tid + k * 256;
    int x = idx / 48, xs = idx - x * 48;
    float v = 0.0f;
    #pragma unroll
    for (int dy = 0; dy < 3; ++dy)
      #pragma unroll
      for (int dx = 0; dx < 3; ++dx)
        v += Gt[dy][x + dx][xs + dx];
    sc[x][xs] = v * rkl[xs];
  }
  __syncthreads();
  if (tid < 48) {
    float best = -1e30f; int bxs = 0;
    for (int xs = 0; xs < 48; ++xs) {
      float v = sc[tid][xs];
      if (v > best) { best = v; bxs = xs; }   // strict >: smallest xs on ties
    }
    int ps = ys * 48 + bxs;
    unsigned ub = __float_as_uint(best);
    unsigned enc = (ub & 0x80000000u) ? ~ub : (ub | 0x80000000u);
    u64 key = ((u64)enc << 32) | (u64)(2303 - ps);
    atomicMax(&rmax[(u64)b * HW + y * 48 + tid], key);
  }
}

// ---------------- reassemble: paste chosen patches + overlap normalize ----------------
__global__ void reassemble_kernel(const float* __restrict__ padS_cl, const u64* __restrict__ rmax,
                                  float* __restrict__ rF_cl) {
  int pix = blockIdx.x, b = blockIdx.y;
  int y = pix / 48, x = pix % 48;
  const u64* rm = rmax + (u64)b * HW;
  const float* S = padS_cl + (u64)b * (NPIX * NC);
  int ch = threadIdx.x;
  float sum = 0.0f;
  #pragma unroll
  for (int i = 0; i < 3; ++i)
    #pragma unroll
    for (int j = 0; j < 3; ++j) {
      int yn = y + 1 - i, xn = x + 1 - j;
      if (yn >= 0 && yn < 48 && xn >= 0 && xn < 48) {
        int ps = 2303 - (int)(unsigned)(rm[yn * 48 + xn] & 0xFFFFFFFFu);
        int ys = ps / 48, xs = ps % 48;
        sum += S[((ys + i) * 50 + xs + j) * NC + ch];
      }
    }
  float cy = (y == 0 || y == 47) ? 2.0f : 3.0f;
  float cx = (x == 0 || x == 47) ? 2.0f : 3.0f;
  rF_cl[(u64)b * (HW * NC) + pix * NC + ch] = sum / (cy * cx);
}

// ---------------- coloring: 64x64 tile, 4x4/thread, float4 LDS ----------------
__launch_bounds__(256)
__global__ void coloring_kernel(const float* __restrict__ Yf, const double* __restrict__ snorm,
                                const double* __restrict__ mean, const float* __restrict__ rF_cl,
                                float* __restrict__ out) {
  int b = blockIdx.z;
  const float* A = Yf + (2 + b) * MATSZ;
  const float* Bp = rF_cl + (u64)b * (HW * NC);
  const double* mn = mean + (2 + b) * NC;
  float cscale = (float)sqrt(snorm[2 + b]);
  int m0 = blockIdx.y * 64, n0 = blockIdx.x * 64;
  __shared__ float As[16][68], Bs[16][68];
  int tid = threadIdx.x;
  int tx = tid & 15, ty = tid >> 4;
  int li = tid >> 2, lk4 = tid & 3;
  int pix = tid >> 2, kq = (tid & 3) * 4;
  float acc[4][4] = {};
  for (int kc = 0; kc < 256; kc += 16) {
    __syncthreads();
    float4 va = *(const float4*)&A[(u64)(m0 + li) * NC + kc + lk4 * 4];
    As[lk4 * 4 + 0][li] = va.x; As[lk4 * 4 + 1][li] = va.y;
    As[lk4 * 4 + 2][li] = va.z; As[lk4 * 4 + 3][li] = va.w;
    float4 vb = *(const float4*)&Bp[(u64)(n0 + pix) * NC + kc + kq];
    Bs[kq + 0][pix] = vb.x; Bs[kq + 1][pix] = vb.y;
    Bs[kq + 2][pix] = vb.z; Bs[kq + 3][pix] = vb.w;
    __syncthreads();
    #pragma unroll
    for (int kk = 0; kk < 16; ++kk) {
      float4 a = *(const float4*)&As[kk][ty * 4];
      float4 b2 = *(const float4*)&Bs[kk][tx * 4];
      float av[4] = {a.x, a.y, a.z, a.w};
      float bv[4] = {b2.x, b2.y, b2.z, b2.w};
      #pragma unroll
      for (int i = 0; i < 4; ++i)
        #pragma unroll
        for (int j = 0; j < 4; ++j) acc[i][j] += av[i] * bv[j];
    }
  }
  #pragma unroll
  for (int i = 0; i < 4; ++i) {
    int row = m0 + ty * 4 + i;
    float madd = (float)mn[row];
    float4 v = make_float4(acc[i][0] * cscale + madd, acc[i][1] * cscale + madd,
                           acc[i][2] * cscale + madd, acc[i][3] * cscale + madd);
    *(float4*)&out[(u64)b * (NC * HW) + (u64)row * HW + n0 + tx * 4] = v;
  }
}

// ---------------- host ----------------
extern "C" void kernel_launch(void* const* d_in, const int* in_sizes, int n_in,
                              void* d_out, int out_size, void* d_ws, size_t ws_size,
                              hipStream_t stream) {
  const float* c = (const float*)d_in[0];
  const float* s = (const float*)d_in[1];
  float* out = (float*)d_out;

  char* ws = (char*)d_ws;
  size_t off = 0;
  auto alloc = [&](size_t bytes) {
    void* p = ws + off;
    off = (off + bytes + 255) & ~(size_t)255;
    return p;
  };
  double* mean   = (double*)alloc(4 * NC * sizeof(double));
  float* covp    = (float*)alloc((size_t)4 * NSLAB * MATSZ * sizeof(float));
  float* Ya      = (float*)alloc((size_t)4 * MATSZ * sizeof(float));
  float* Yb      = (float*)alloc((size_t)4 * MATSZ * sizeof(float));
  float* Za      = (float*)alloc((size_t)4 * MATSZ * sizeof(float));
  float* Zb      = (float*)alloc((size_t)4 * MATSZ * sizeof(float));
  float* T       = (float*)alloc((size_t)4 * MATSZ * sizeof(float));
  float* padC_cf = (float*)alloc((size_t)2 * NC * NPIXP * sizeof(float));
  float* padS_cf = (float*)alloc((size_t)2 * NC * NPIXP * sizeof(float));
  float* padS_cl = (float*)alloc((size_t)2 * NPIX * NC * sizeof(float));
  ushortt* padCk_hi = (ushortt*)alloc((size_t)2 * PMSZ * sizeof(ushortt));
  ushortt* padCk_lo = (ushortt*)alloc((size_t)2 * PMSZ * sizeof(ushortt));
  ushortt* padSk_hi = (ushortt*)alloc((size_t)2 * PMSZ * sizeof(ushortt));
  ushortt* padSk_lo = (ushortt*)alloc((size_t)2 * PMSZ * sizeof(ushortt));
  float* ssq     = (float*)alloc((size_t)2 * NPIX * sizeof(float));
  float* rF_cl   = (float*)alloc((size_t)2 * HW * NC * sizeof(float));
  float* G       = (float*)alloc((size_t)2 * GSZ * sizeof(float));
  u64*   rmax    = (u64*)alloc((size_t)2 * HW * sizeof(u64));
  double* snorm  = (double*)alloc(4 * sizeof(double));

  size_t padBytes = (size_t)(2 * NC * NPIXP + 2 * NC * NPIXP + 2 * NPIX * NC) * sizeof(float);
  hipMemsetAsync(padC_cf, 0, padBytes, stream);
  hipMemsetAsync(rmax, 0, (size_t)2 * HW * sizeof(u64) + 4 * sizeof(double), stream);

  mean_kernel<<<dim3(256, 4), 64, 0, stream>>>(c, s, mean, snorm);
  cov_part<<<dim3(4, 4, 4 * NSLAB), dim3(16, 16), 0, stream>>>(c, s, covp);
  // NS iter0 folded: Ya = Y0, Za = T0 = Z1
  cov_reduce<<<dim3(256, 4), 256, 0, stream>>>(covp, mean, snorm, Ya, Za);
  ns_gemm_Y<<<dim3(8, 8, 4), dim3(16, 16), 0, stream>>>(Ya, Za, Yb);  // Y1 = Y0*T0

  float *Yc = Yb, *Zc = Za, *Yn = Ya, *Zn = Zb;
  for (int it = 1; it < NS_ITERS; ++it) {
    ns_gemm_T<<<dim3(8, 8, 4), dim3(16, 16), 0, stream>>>(Zc, Yc, T);
    ns_gemm_YZ<<<dim3(8, 8, 8), dim3(16, 16), 0, stream>>>(Yc, Zc, T, Yn, Zn);
    float* t1 = Yc; Yc = Yn; Yn = t1;
    float* t2 = Zc; Zc = Zn; Zn = t2;
  }

  whiten_kernel<<<dim3(36, 4, 4), 256, 0, stream>>>(c, s, Zc, snorm, mean,
                                                    padC_cf, padS_cf, padS_cl);
  tsplit_kernel<<<dim3(40, 4), 256, 0, stream>>>(padC_cf, padS_cf,
                                                 padCk_hi, padCk_lo, padSk_hi, padSk_lo, ssq);

  gram_mfma<<<dim3(20, 40, 2), 256, 0, stream>>>(padCk_hi, padCk_lo, padSk_hi, padSk_lo, G);
  scoremax_kernel<<<dim3(48, 48, 2), 256, 0, stream>>>(G, ssq, rmax);

  reassemble_kernel<<<dim3(2304, 2), 256, 0, stream>>>(padS_cl, rmax, rF_cl);
  coloring_kernel<<<dim3(36, 4, 2), 256, 0, stream>>>(Yc, snorm, mean, rF_cl, out);
}